// Round 1
// 917.084 us; speedup vs baseline: 1.0116x; 1.0116x over previous
//
#include <hip/hip_runtime.h>
#include <math.h>

// ---------------------------------------------------------------------------
// Problem constants: B=1024, XDIM=62, TWIN=10, INCH=128, MID=256, OUT=512,
// K=3, K1=10, LIN=512.  REGIONS partition nodes 0..61 exactly once.
// hc_b1/hc_b2 dropped: BN subtracts the batch mean -> bias-invariant.
// Round 1 changes vs 924us baseline:
//  - k_prep_all + k_g merged into k_front (one dispatch); k_g now loads
//    float4 (16B/lane) with 8 rows/block.
//  - k_softcat: per-thread LDS array -> registers (occupancy 2 -> ~5 w/SIMD).
//  - reduce/stats/bngelu (3 kernels) -> k_reduce_stats (atomic col sums) +
//    k_bngelu2 (finalizes mu/rs inline). H1 stats pass eliminated.
//  - h2 GEMM split-K=4 (16 -> 64 blocks); k_stats2r fuses partial-reduce +
//    H2 write + bn2 stats.
// ---------------------------------------------------------------------------

// concat order of nodes (p -> node)
__constant__ int cOrder[62] = {
  0,1,2,3,4,
  5,6,7,14,15,16,
  8,9,10,17,18,19,
  11,12,13,20,21,22,
  23,24,25,32,33,34,
  26,27,28,35,36,37,
  29,30,31,38,39,40,
  41,42,43,50,51,57,
  44,45,46,52,53,54,58,59,60,
  47,48,49,55,56,61
};
// node -> position in concat order
__constant__ int cPos[62] = {
  0,1,2,3,4, 5,6,7, 11,12,13, 17,18,19, 8,9,10, 14,15,16, 20,21,22,
  23,24,25, 29,30,31, 35,36,37, 26,27,28, 32,33,34, 38,39,40,
  41,42,43, 47,48,49, 56,57,58, 44,45, 50,51,52, 59,60, 46, 53,54,55, 61
};
// per-region K (=L*128) and cumulative k offset
__constant__ int cRegK[10]   = {640,768,768,768,768,768,768,768,1152,768};
__constant__ int cRegCum[10] = {0,640,1408,2176,2944,3712,4480,5248,6016,7168};

struct Ptr10 { const float* p[10]; };

typedef __attribute__((ext_vector_type(8))) short bf16x8;
typedef __attribute__((ext_vector_type(4))) float f32x4;

__device__ __forceinline__ float gelu_exact(float v){
  return 0.5f * v * (1.0f + erff(v * 0.70710678118654752f));
}
__device__ __forceinline__ unsigned short f2bf(float f){
  unsigned u = __float_as_uint(f);
  unsigned r = (u + 0x7fffu + ((u >> 16) & 1u)) >> 16;
  return (unsigned short)r;
}
__device__ __forceinline__ float bf2f(unsigned short u){
  return __uint_as_float(((unsigned)u) << 16);
}
__device__ __forceinline__ void load_lds16(const unsigned short* g, unsigned short* l){
  __builtin_amdgcn_global_load_lds(
      (const __attribute__((address_space(1))) void*)g,
      (__attribute__((address_space(3))) void*)l, 16, 0, 0);
}

// ---------------------------------------------------------------------------
// MFMA GEMM: C(MxN) = A(MxK) @ BT(NxK)^T, bf16 in, fp32 acc. 128x128 tile,
// BK=32, XOR-swizzled LDS, global_load_lds w=16.
// mcCount>0: 1-D grid with XCD-cluster swizzle (2m x 4n clusters per XCD).
// mcCount==0: plain 3-D grid. RELU=true: bf16+relu store; else fp32 partial.
// ---------------------------------------------------------------------------
template<bool RELU>
__global__ __launch_bounds__(256) void k_mfma(
    const unsigned short* __restrict__ A, long lda,
    const unsigned short* __restrict__ BT, long ldb,
    void* __restrict__ Cv, int ldc, int kPerZ, long cStrideZ, int mcCount){
  __shared__ unsigned short As[128*32];
  __shared__ unsigned short Bs[128*32];
  int mt, nt, zt;
  if (mcCount){
    int id = blockIdx.x;
    int c = ((id >> 6) << 3) + (id & 7);   // cluster index
    int member = (id >> 3) & 7;
    zt = c / mcCount;
    int mc = c - zt*mcCount;
    mt = mc*2 + (member >> 2);
    nt = member & 3;
  } else { mt = blockIdx.x; nt = blockIdx.y; zt = blockIdx.z; }
  int tid = threadIdx.x;
  int wave = tid >> 6, lane = tid & 63;
  int m0 = mt * 128, n0 = nt * 128;
  int kStart = zt * kPerZ;
  int waveM = wave >> 1, waveN = wave & 1;
  int lr = lane >> 2, ch = lane & 3;
  int quad = lane >> 4, mrow = lane & 15;
  int swe = ((quad ^ (mrow & 3)) << 3);

  int rA0 = wave*32 + lr;
  int rA1 = rA0 + 16;
  int ce  = ((ch ^ (rA0 & 3)) << 3);
  const unsigned short* gA0 = A  + (long)(m0 + rA0)*lda + kStart + ce;
  const unsigned short* gA1 = A  + (long)(m0 + rA1)*lda + kStart + ce;
  const unsigned short* gB0 = BT + (long)(n0 + rA0)*ldb + kStart + ce;
  const unsigned short* gB1 = BT + (long)(n0 + rA1)*ldb + kStart + ce;
  unsigned short* lA0 = &As[(wave*32)*32];
  unsigned short* lA1 = &As[(wave*32+16)*32];
  unsigned short* lB0 = &Bs[(wave*32)*32];
  unsigned short* lB1 = &Bs[(wave*32+16)*32];

  f32x4 acc[4][4] = {};
  int nIter = kPerZ >> 5;
  for (int it = 0; it < nIter; ++it){
    long ko = (long)it << 5;
    load_lds16(gA0 + ko, lA0);
    load_lds16(gA1 + ko, lA1);
    load_lds16(gB0 + ko, lB0);
    load_lds16(gB1 + ko, lB1);
    __syncthreads();
    bf16x8 af[4], bfr[4];
#pragma unroll
    for (int mi = 0; mi < 4; mi++)
      af[mi] = *(const bf16x8*)&As[(waveM*64 + mi*16 + mrow)*32 + swe];
#pragma unroll
    for (int ni = 0; ni < 4; ni++)
      bfr[ni] = *(const bf16x8*)&Bs[(waveN*64 + ni*16 + mrow)*32 + swe];
#pragma unroll
    for (int mi = 0; mi < 4; mi++)
#pragma unroll
      for (int ni = 0; ni < 4; ni++)
        acc[mi][ni] = __builtin_amdgcn_mfma_f32_16x16x32_bf16(
            af[mi], bfr[ni], acc[mi][ni], 0, 0, 0);
    __syncthreads();
  }
  if (RELU){
    unsigned short* C = (unsigned short*)Cv;
#pragma unroll
    for (int mi = 0; mi < 4; mi++)
#pragma unroll
      for (int ni = 0; ni < 4; ni++){
        int col = n0 + waveN*64 + ni*16 + mrow;
#pragma unroll
        for (int r = 0; r < 4; r++){
          int row = m0 + waveM*64 + mi*16 + quad*4 + r;
          C[(long)row*ldc + col] = f2bf(fmaxf(acc[mi][ni][r], 0.f));
        }
      }
  } else {
    float* C = (float*)Cv + (long)zt * cStrideZ;
#pragma unroll
    for (int mi = 0; mi < 4; mi++)
#pragma unroll
      for (int ni = 0; ni < 4; ni++){
        int col = n0 + waveN*64 + ni*16 + mrow;
#pragma unroll
        for (int r = 0; r < 4; r++){
          int row = m0 + waveM*64 + mi*16 + quad*4 + r;
          C[(long)row*ldc + col] = acc[mi][ni][r];
        }
      }
  }
}
template __global__ void k_mfma<true>(const unsigned short*, long, const unsigned short*, long, void*, int, int, long, int);
template __global__ void k_mfma<false>(const unsigned short*, long, const unsigned short*, long, void*, int, int, long, int);

// ---------------------------------------------------------------------------
// Region MFMA: g2in[b, z*256+m] = sum_k ARb[b, cum_z+k] * RWT_z[m,k] + regb[z,m]
// grid (8, 2, 10).
// ---------------------------------------------------------------------------
__global__ __launch_bounds__(256) void k_mfma_region(
    const unsigned short* __restrict__ ARb,
    const unsigned short* __restrict__ RWT,
    const float* __restrict__ regb, float* __restrict__ g2in){
  __shared__ unsigned short As[128*32];
  __shared__ unsigned short Bs[128*32];
  int z = blockIdx.z;
  int K = cRegK[z];
  int cumk = cRegCum[z];
  const unsigned short* A  = ARb + cumk;
  const unsigned short* BT = RWT + (long)cumk*256;
  long lda = 7936, ldb = K;
  int tid = threadIdx.x;
  int wave = tid >> 6, lane = tid & 63;
  int m0 = blockIdx.x * 128, n0 = blockIdx.y * 128;
  int waveM = wave >> 1, waveN = wave & 1;
  int lr = lane >> 2, ch = lane & 3;
  int quad = lane >> 4, mrow = lane & 15;
  int swe = ((quad ^ (mrow & 3)) << 3);

  int rA0 = wave*32 + lr;
  int rA1 = rA0 + 16;
  int ce  = ((ch ^ (rA0 & 3)) << 3);
  const unsigned short* gA0 = A  + (long)(m0 + rA0)*lda + ce;
  const unsigned short* gA1 = A  + (long)(m0 + rA1)*lda + ce;
  const unsigned short* gB0 = BT + (long)(n0 + rA0)*ldb + ce;
  const unsigned short* gB1 = BT + (long)(n0 + rA1)*ldb + ce;
  unsigned short* lA0 = &As[(wave*32)*32];
  unsigned short* lA1 = &As[(wave*32+16)*32];
  unsigned short* lB0 = &Bs[(wave*32)*32];
  unsigned short* lB1 = &Bs[(wave*32+16)*32];

  f32x4 acc[4][4] = {};
  int nIter = K >> 5;
  for (int it = 0; it < nIter; ++it){
    long ko = (long)it << 5;
    load_lds16(gA0 + ko, lA0);
    load_lds16(gA1 + ko, lA1);
    load_lds16(gB0 + ko, lB0);
    load_lds16(gB1 + ko, lB1);
    __syncthreads();
    bf16x8 af[4], bfr[4];
#pragma unroll
    for (int mi = 0; mi < 4; mi++)
      af[mi] = *(const bf16x8*)&As[(waveM*64 + mi*16 + mrow)*32 + swe];
#pragma unroll
    for (int ni = 0; ni < 4; ni++)
      bfr[ni] = *(const bf16x8*)&Bs[(waveN*64 + ni*16 + mrow)*32 + swe];
#pragma unroll
    for (int mi = 0; mi < 4; mi++)
#pragma unroll
      for (int ni = 0; ni < 4; ni++)
        acc[mi][ni] = __builtin_amdgcn_mfma_f32_16x16x32_bf16(
            af[mi], bfr[ni], acc[mi][ni], 0, 0, 0);
    __syncthreads();
  }
#pragma unroll
  for (int mi = 0; mi < 4; mi++)
#pragma unroll
    for (int ni = 0; ni < 4; ni++){
      int col = n0 + waveN*64 + ni*16 + mrow;
      float bias = regb[z*256 + col];
#pragma unroll
      for (int r = 0; r < 4; r++){
        int row = m0 + waveM*64 + mi*16 + quad*4 + r;
        g2in[(long)row*2560 + z*256 + col] = acc[mi][ni][r] + bias;
      }
    }
}

// ---------------------------------------------------------------------------
// k_front: one dispatch for all input-only work.
//   [0,4784)        : 64x64 fp32->bf16 transpose tiles (hc_w1/hc_w2/ch1w/ch2w)
//   [4784,7344)     : region-weight transpose
//   [7344,7406)     : A-transpose + (A@A)^T
//   [7406,15342)    : g-kernel, 8 (b,n) rows/block, float4 channel loads
//   15342           : zero the bn1 atomic accumulators (1024 floats)
// ---------------------------------------------------------------------------
__global__ __launch_bounds__(256) void k_front(
    const float* __restrict__ s0, unsigned short* __restrict__ d0,
    const float* __restrict__ s1, unsigned short* __restrict__ d1,
    const float* __restrict__ s2, unsigned short* __restrict__ d2,
    const float* __restrict__ s3, unsigned short* __restrict__ d3,
    Ptr10 rws, unsigned short* __restrict__ RWT,
    const float* __restrict__ Amat, float* __restrict__ AT,
    float* __restrict__ A2T,
    const float* __restrict__ x, const float* __restrict__ tw,
    const float* __restrict__ tb, unsigned short* __restrict__ arb,
    unsigned short* __restrict__ xcat, float* __restrict__ sumz){
  __shared__ float smem[64*65];
  int id = blockIdx.x;
  int tid = threadIdx.x;
  if (id >= 15342){
    *(float4*)(sumz + tid*4) = make_float4(0.f,0.f,0.f,0.f);
    return;
  }
  if (id >= 7406){
    // g[b,n,c] = (sum_i x*tfe_w + tfe_b) * exp(-var_i(x)) (ddof=1), bf16 out
    int q = id - 7406;
    int r = tid >> 5, j = tid & 31;        // 8 rows x 32 lanes, 4 ch/lane
    int idx = q*8 + r;                      // b*62+n
    int b = idx / 62, n = idx - b*62;
    const float4* xp = (const float4*)(x + (long)idx*1280) + j;
    float sx=0.f,sy=0.f,sz=0.f,sw=0.f;
    float qx=0.f,qy=0.f,qz=0.f,qw=0.f;
    float gx=0.f,gy=0.f,gz=0.f,gw=0.f;
#pragma unroll
    for (int i = 0; i < 10; i++){
      float4 v = xp[i*32];
      float w = tw[n*10+i];
      sx+=v.x; sy+=v.y; sz+=v.z; sw+=v.w;
      qx=fmaf(v.x,v.x,qx); qy=fmaf(v.y,v.y,qy);
      qz=fmaf(v.z,v.z,qz); qw=fmaf(v.w,v.w,qw);
      gx=fmaf(v.x,w,gx); gy=fmaf(v.y,w,gy);
      gz=fmaf(v.z,w,gz); gw=fmaf(v.w,w,gw);
    }
    float tbn = tb[n];
    float mx_=sx*0.1f, my_=sy*0.1f, mz_=sz*0.1f, mw_=sw*0.1f;
    float rx = (gx+tbn)*expf(-(qx-10.f*mx_*mx_)*(1.f/9.f));
    float ry = (gy+tbn)*expf(-(qy-10.f*my_*my_)*(1.f/9.f));
    float rz = (gz+tbn)*expf(-(qz-10.f*mz_*mz_)*(1.f/9.f));
    float rw = (gw+tbn)*expf(-(qw-10.f*mw_*mw_)*(1.f/9.f));
    ushort4 u = make_ushort4(f2bf(rx), f2bf(ry), f2bf(rz), f2bf(rw));
    *(ushort4*)(arb  + (long)b*7936  + cPos[n]*128 + j*4) = u;
    *(ushort4*)(xcat + (long)b*23808 + n*384       + j*4) = u;
    return;
  }
  if (id < 7344 && id >= 4784){
    // region-weight transpose: RWT[cum+m*K + l*128+c] = bf16(rw[m][c*L+l])
    int q = id - 4784;
    int z = q >> 8, m = q & 255;
    int K = cRegK[z], L = K >> 7;
    const float* rw = rws.p[z] + (long)m*K;
    unsigned short* dst = RWT + (long)cRegCum[z]*256 + (long)m*K;
    for (int i = tid; i < K; i += 256) smem[i] = rw[i];
    __syncthreads();
    for (int k = tid; k < K; k += 256){
      int l = k >> 7, c = k & 127;
      dst[k] = f2bf(smem[c*L + l]);
    }
    return;
  }
  if (id >= 7344){
    // A helpers, one row per block
    int r = id - 7344, c = tid;
    if (c < 62) smem[c] = Amat[r*62 + c];
    __syncthreads();
    if (c < 62){
      AT[c*62 + r] = smem[c];
      float s = 0.f;
      for (int t = 0; t < 62; t++) s = fmaf(smem[t], Amat[t*62 + c], s);
      A2T[c*62 + r] = s;
    }
    return;
  }
  // 64x64 fp32->bf16 transpose tiles
  const float* src; unsigned short* dst; int R, C, rt, ct;
  if (id < 4608){ src=s0; dst=d0; R=36864; C=512; rt=id>>3;  ct=id&7; }
  else if (id < 4640){ int q=id-4608; src=s1; dst=d1; R=512; C=256; rt=q>>2; ct=q&3; }
  else if (id < 4688){ int q=id-4640; src=s2; dst=d2; R=384; C=512; rt=q>>3; ct=q&7; }
  else { int q=id-4688; src=s3; dst=d3; R=768; C=512; rt=q>>3; ct=q&7; }
  int r0 = rt*64, c0 = ct*64;
  int rr = tid >> 2, cb = (tid & 3) << 2;
#pragma unroll
  for (int i = 0; i < 4; i++){
    int cc = cb + i*16;
    float4 v = *(const float4*)(src + (long)(r0+rr)*C + c0 + cc);
    smem[rr*65+cc+0]=v.x; smem[rr*65+cc+1]=v.y;
    smem[rr*65+cc+2]=v.z; smem[rr*65+cc+3]=v.w;
  }
  __syncthreads();
  int cc = tid >> 2, rb = (tid & 3) << 2;
#pragma unroll
  for (int i = 0; i < 4; i++){
    int r = rb + i*16;
    ushort4 u = make_ushort4(f2bf(smem[(r+0)*65+cc]), f2bf(smem[(r+1)*65+cc]),
                             f2bf(smem[(r+2)*65+cc]), f2bf(smem[(r+3)*65+cc]));
    *(ushort4*)(dst + (long)(c0+cc)*R + r0 + r) = u;
  }
}

// ---------------------------------------------------------------------------
// 2) fused spread: XCAT slot1 = bf16(A @ g_b), slot2 = bf16(A^2 @ g_b).
//    One block per b; 256 thr = 128 c x 2 mats; A rows via uniform scalar loads.
// ---------------------------------------------------------------------------
__global__ __launch_bounds__(256) void k_spread2(
    const unsigned short* __restrict__ ARb, const float* __restrict__ AT,
    const float* __restrict__ A2T, unsigned short* __restrict__ xcat){
  __shared__ float sgn[7936];
  int b = blockIdx.x, tid = threadIdx.x;
  for (int i = tid; i < 7936; i += 256){
    int p = i >> 7, c = i & 127;
    sgn[cOrder[p]*128 + c] = bf2f(ARb[(long)b*7936 + i]);
  }
  __syncthreads();
  int c = tid & 127, mat = tid >> 7;      // mat uniform per wave
  const float* MT = mat ? A2T : AT;
  float acc[62];
#pragma unroll
  for (int n = 0; n < 62; n++) acc[n] = 0.f;
  for (int m = 0; m < 62; m++){
    float gv = sgn[m*128 + c];
    const float* Mp = MT + m*62;          // contiguous row -> scalar loads
#pragma unroll
    for (int n = 0; n < 62; n++) acc[n] = fmaf(Mp[n], gv, acc[n]);
  }
  long base = (long)b*23808 + (mat+1)*128 + c;
#pragma unroll
  for (int n = 0; n < 62; n++) xcat[base + (long)n*384] = f2bf(acc[n]);
}

// ---------------------------------------------------------------------------
// 4) X2cat[b, n, k*256+t] = (A1^k @ g2in[b])[n,t], k=0..2  (bf16 out)
// ---------------------------------------------------------------------------
__global__ __launch_bounds__(256) void k_x2cat(
    const float* __restrict__ g2in, const float* __restrict__ A1,
    unsigned short* __restrict__ X2){
  __shared__ float sg[2560];
  __shared__ float sA1[100];
  __shared__ float sA2[100];
  int b = blockIdx.x, tid = threadIdx.x;
  for (int i = tid; i < 2560; i += 256) sg[i] = g2in[(long)b*2560 + i];
  if (tid < 100) sA1[tid] = A1[tid];
  __syncthreads();
  if (tid < 100){
    int n = tid/10, m = tid - n*10;
    float a = 0.f;
#pragma unroll
    for (int t = 0; t < 10; t++) a = fmaf(sA1[n*10+t], sA1[t*10+m], a);
    sA2[tid] = a;
  }
  __syncthreads();
  for (int i = tid; i < 2560; i += 256){
    int n = i >> 8, t = i & 255;
    float v1 = 0.f, v2 = 0.f;
#pragma unroll
    for (int m = 0; m < 10; m++){
      float gv = sg[(m<<8) + t];
      v1 = fmaf(sA1[n*10+m], gv, v1);
      v2 = fmaf(sA2[n*10+m], gv, v2);
    }
    long base = (long)b*7680 + n*768;
    X2[base + t]       = f2bf(sg[i]);
    X2[base + 256 + t] = f2bf(v1);
    X2[base + 512 + t] = f2bf(v2);
  }
}

// ---------------------------------------------------------------------------
// 6) softmax-gated concat, all per-thread state in registers (no LDS).
//    grid (1024, 2) x 256 thr; thread owns one (b, o) column.
// ---------------------------------------------------------------------------
__global__ __launch_bounds__(256) void k_softcat(
    const unsigned short* __restrict__ g1, const unsigned short* __restrict__ g2,
    const float* __restrict__ bg_, const float* __restrict__ cg_,
    unsigned short* __restrict__ outb){
  int b = blockIdx.x;
  int o = blockIdx.y*256 + threadIdx.x;
  float v[72];
  const unsigned short* p1 = g1 + (long)b*62*512 + o;
#pragma unroll
  for (int j = 0; j < 62; j++) v[j] = bf2f(p1[j*512]);
  const unsigned short* p2 = g2 + (long)b*10*512 + o;
#pragma unroll
  for (int j = 0; j < 10; j++) v[62+j] = bf2f(p2[j*512]);
  float bg = *bg_, cg = *cg_;
  float mx = -1e30f;
#pragma unroll
  for (int j = 0; j < 72; j++){
    float av = (j < 62 ? bg : cg) * v[j];
    mx = fmaxf(mx, av);
  }
  float sum = 0.f;
#pragma unroll
  for (int j = 0; j < 72; j++){
    float e = expf((j < 62 ? bg : cg) * v[j] - mx);
    sum += e;
    v[j] = e * v[j];
  }
  float inv = 1.f / sum;
  unsigned short* op = outb + (long)b*36864 + o;
#pragma unroll
  for (int j = 0; j < 72; j++) op[j*512] = f2bf(v[j] * inv);
}

// ---------------------------------------------------------------------------
// 8) reduce 16 split-K partials -> h1 (1024 x 512) fp32 AND accumulate
//    per-column sum / sumsq via fp32 atomics (accumulators zeroed in k_front).
//    128 blocks x 256 thr; block = 8 rows x 512 cols.
// ---------------------------------------------------------------------------
__global__ __launch_bounds__(256) void k_reduce_stats(
    const float4* __restrict__ P, float4* __restrict__ h1,
    float* __restrict__ sum, float* __restrict__ ssq){
  __shared__ float4 ls[128], ls2[128];
  int c  = threadIdx.x & 127;        // float4-column
  int rr = threadIdx.x >> 7;         // 0/1
  int r0 = blockIdx.x * 8;
  float4 s1 = make_float4(0.f,0.f,0.f,0.f);
  float4 s2 = make_float4(0.f,0.f,0.f,0.f);
#pragma unroll
  for (int k = 0; k < 4; k++){
    int row = r0 + rr + 2*k;
    long idx = (long)row*128 + c;
    float4 v = make_float4(0.f,0.f,0.f,0.f);
#pragma unroll
    for (int s = 0; s < 16; s++){
      float4 p = P[(long)s*131072 + idx];
      v.x += p.x; v.y += p.y; v.z += p.z; v.w += p.w;
    }
    h1[idx] = v;
    s1.x += v.x; s1.y += v.y; s1.z += v.z; s1.w += v.w;
    s2.x = fmaf(v.x,v.x,s2.x); s2.y = fmaf(v.y,v.y,s2.y);
    s2.z = fmaf(v.z,v.z,s2.z); s2.w = fmaf(v.w,v.w,s2.w);
  }
  if (rr){ ls[c] = s1; ls2[c] = s2; }
  __syncthreads();
  if (!rr){
    float4 o1 = ls[c], o2 = ls2[c];
    atomicAdd(&sum[c*4+0], s1.x+o1.x); atomicAdd(&sum[c*4+1], s1.y+o1.y);
    atomicAdd(&sum[c*4+2], s1.z+o1.z); atomicAdd(&sum[c*4+3], s1.w+o1.w);
    atomicAdd(&ssq[c*4+0], s2.x+o2.x); atomicAdd(&ssq[c*4+1], s2.y+o2.y);
    atomicAdd(&ssq[c*4+2], s2.z+o2.z); atomicAdd(&ssq[c*4+3], s2.w+o2.w);
  }
}

// 9) H1B = bf16(gelu(bn1(h1))), mu/rs finalized inline from atomic sums
__global__ __launch_bounds__(256) void k_bngelu(
    const float* __restrict__ h1, const float* __restrict__ sum,
    const float* __restrict__ ssq, const float* __restrict__ gam,
    const float* __restrict__ bet, unsigned short* __restrict__ h1b){
  int base = (blockIdx.x*256 + threadIdx.x) * 4;
  int j = base & 511;
  float4 v = *(const float4*)(h1 + base);
  float mu0 = sum[j+0]*(1.f/1024.f), mu1 = sum[j+1]*(1.f/1024.f);
  float mu2 = sum[j+2]*(1.f/1024.f), mu3 = sum[j+3]*(1.f/1024.f);
  float rs0 = rsqrtf(ssq[j+0]*(1.f/1024.f) - mu0*mu0 + 1e-5f);
  float rs1 = rsqrtf(ssq[j+1]*(1.f/1024.f) - mu1*mu1 + 1e-5f);
  float rs2 = rsqrtf(ssq[j+2]*(1.f/1024.f) - mu2*mu2 + 1e-5f);
  float rs3 = rsqrtf(ssq[j+3]*(1.f/1024.f) - mu3*mu3 + 1e-5f);
  ushort4 u;
  u.x = f2bf(gelu_exact((v.x - mu0)*rs0*gam[j+0] + bet[j+0]));
  u.y = f2bf(gelu_exact((v.y - mu1)*rs1*gam[j+1] + bet[j+1]));
  u.z = f2bf(gelu_exact((v.z - mu2)*rs2*gam[j+2] + bet[j+2]));
  u.w = f2bf(gelu_exact((v.w - mu3)*rs3*gam[j+3] + bet[j+3]));
  *(ushort4*)(h1b + base) = u;
}

// 10b) reduce 4 split-K h2 partials -> H2 fp32, + bn2 stats. 32 blocks.
__global__ __launch_bounds__(256) void k_stats2r(
    const float* __restrict__ P2, float* __restrict__ h2,
    float* __restrict__ mu, float* __restrict__ rs){
  __shared__ float lsm[256], lss[256];
  int j0 = blockIdx.x * 8;
  int jj = threadIdx.x & 7, bg = threadIdx.x >> 3;
  float s = 0.f, s2 = 0.f;
#pragma unroll 4
  for (int it = 0; it < 32; it++){
    int row = it*32 + bg;
    float v = 0.f;
#pragma unroll
    for (int sp = 0; sp < 4; sp++)
      v += P2[((long)sp*1024 + row)*256 + j0 + jj];
    h2[(long)row*256 + j0 + jj] = v;
    s += v; s2 = fmaf(v, v, s2);
  }
  lsm[threadIdx.x] = s; lss[threadIdx.x] = s2;
  __syncthreads();
  if (threadIdx.x < 8){
    float a = lsm[threadIdx.x], a2 = lss[threadIdx.x];
    for (int g = 1; g < 32; g++){ a += lsm[g*8 + threadIdx.x]; a2 += lss[g*8 + threadIdx.x]; }
    float m = a * (1.f/1024.f);
    float var = a2 * (1.f/1024.f) - m*m;
    mu[j0 + threadIdx.x] = m;
    rs[j0 + threadIdx.x] = rsqrtf(var + 1e-5f);
  }
}

// 11) final: bn2+gelu, @ hc_w3 + hc_b3, softmax over 4 -> d_out
__global__ __launch_bounds__(256) void k_final(
    const float* __restrict__ h2, const float* __restrict__ mu,
    const float* __restrict__ rs, const float* __restrict__ gam,
    const float* __restrict__ bet, const float* __restrict__ w3,
    const float* __restrict__ b3, float* __restrict__ outp){
  int b = blockIdx.x, tid = threadIdx.x;
  float v = h2[(long)b*256 + tid];
  v = (v - mu[tid]) * rs[tid] * gam[tid] + bet[tid];
  v = gelu_exact(v);
  float4 w = ((const float4*)w3)[tid];
  float p0 = v*w.x, p1 = v*w.y, p2 = v*w.z, p3 = v*w.w;
#pragma unroll
  for (int o = 32; o > 0; o >>= 1){
    p0 += __shfl_down(p0, o);
    p1 += __shfl_down(p1, o);
    p2 += __shfl_down(p2, o);
    p3 += __shfl_down(p3, o);
  }
  __shared__ float red[4][4];
  int wv = tid >> 6;
  if ((tid & 63) == 0){ red[wv][0]=p0; red[wv][1]=p1; red[wv][2]=p2; red[wv][3]=p3; }
  __syncthreads();
  if (tid == 0){
    float l[4];
#pragma unroll
    for (int c = 0; c < 4; c++)
      l[c] = red[0][c]+red[1][c]+red[2][c]+red[3][c] + b3[c];
    float m = fmaxf(fmaxf(l[0], l[1]), fmaxf(l[2], l[3]));
    float e[4]; float sum = 0.f;
#pragma unroll
    for (int c = 0; c < 4; c++){ e[c] = expf(l[c]-m); sum += e[c]; }
    float inv = 1.f / sum;
#pragma unroll
    for (int c = 0; c < 4; c++) outp[(long)b*4 + c] = e[c]*inv;
  }
}

// ---------------------------------------------------------------------------
// Workspace layout (byte offsets), peak ~248 MB (unchanged).
// ---------------------------------------------------------------------------
extern "C" void kernel_launch(void* const* d_in, const int* in_sizes, int n_in,
                              void* d_out, int out_size, void* d_ws, size_t ws_size,
                              hipStream_t stream){
  (void)n_in; (void)out_size; (void)ws_size;
  bool dictOrder = (in_sizes[9] == 2560);
  const float* x     = (const float*)d_in[0];
  const float* tfe_w = (const float*)d_in[1];
  const float* tfe_b = (const float*)d_in[2];
  const float* ch1w  = (const float*)d_in[3];
  const float* Amat  = (const float*)d_in[4];
  const float* ch2w  = (const float*)d_in[5];
  const float* A1mat = (const float*)d_in[6];
  const float* bgate = (const float*)d_in[7];
  const float* cgate = (const float*)d_in[8];
  const float* regb  = (const float*)d_in[dictOrder ? 9 : 19];
  int o = dictOrder ? 0 : 10;
  const float* hc_w1 = (const float*)d_in[10+o];
  const float* bn1g  = (const float*)d_in[12+o];
  const float* bn1b  = (const float*)d_in[13+o];
  const float* hc_w2 = (const float*)d_in[14+o];
  const float* bn2g  = (const float*)d_in[16+o];
  const float* bn2b  = (const float*)d_in[17+o];
  const float* hc_w3 = (const float*)d_in[18+o];
  const float* hc_b3 = (const float*)d_in[19+o];
  Ptr10 rws;
  for (int i = 0; i < 10; i++) rws.p[i] = (const float*)d_in[(dictOrder ? 20 : 9) + i];

  char* Wb = (char*)d_ws;
  unsigned short* ARb   = (unsigned short*)(Wb + 0);
  unsigned short* XCAT  = (unsigned short*)(Wb + 16252928);
  unsigned short* RWT   = (unsigned short*)(Wb + 65011712);
  float*          G2IN  = (float*)(Wb + 69074944);
  unsigned short* X2CAT = (unsigned short*)(Wb + 79560704);
  unsigned short* W1T   = (unsigned short*)(Wb + 95289344);
  unsigned short* WC1T  = (unsigned short*)(Wb + 133038080);
  unsigned short* WC2T  = (unsigned short*)(Wb + 133431296);
  unsigned short* G1    = (unsigned short*)(Wb + 134217728);
  unsigned short* G2    = (unsigned short*)(Wb + 199229440);
  unsigned short* OUTB  = (unsigned short*)(Wb + 0);
  float*          P     = (float*)(Wb + 209715200);
  float*          H1    = (float*)(Wb + 243269632);
  float*          H2    = (float*)(Wb + 245366784);
  float*          SUM1  = (float*)(Wb + 246415360);   // atomic col sums (bn1)
  float*          SSQ1  = SUM1 + 512;                 // atomic col sumsq (bn1)
  float*          MU2   = SUM1 + 1024;
  float*          RS2   = SUM1 + 1280;
  float*          AT    = (float*)(Wb + 246423552);
  float*          A2T   = (float*)(Wb + 246439040);
  unsigned short* W2T   = (unsigned short*)(Wb + 246454528);
  unsigned short* H1B   = (unsigned short*)(Wb + 246716928);

  // prep transforms + g + accumulator zeroing, one dispatch
  k_front<<<15343, 256, 0, stream>>>(hc_w1, W1T, hc_w2, W2T, ch1w, WC1T,
                                     ch2w, WC2T, rws, RWT, Amat, AT, A2T,
                                     x, tfe_w, tfe_b, ARb, XCAT, SUM1);
  k_spread2<<<1024, 256, 0, stream>>>(ARb, AT, A2T, XCAT);
  k_mfma_region<<<dim3(8,2,10), 256, 0, stream>>>(ARb, RWT, regb, G2IN);
  k_x2cat<<<1024, 256, 0, stream>>>(G2IN, A1mat, X2CAT);
  // cheby2: (10240 x 768) @ (768 x 512), swizzled 320 blocks (mc=40)
  k_mfma<true><<<320, 256, 0, stream>>>(X2CAT, 768, WC2T, 768, (void*)G2, 512, 768, 0, 40);
  // cheby1: (63488 x 384) @ (384 x 512), swizzled 1984 blocks (mc=248)
  k_mfma<true><<<1984, 256, 0, stream>>>(XCAT, 384, WC1T, 384, (void*)G1, 512, 384, 0, 248);
  k_softcat<<<dim3(1024,2), 256, 0, stream>>>(G1, G2, bgate, cgate, OUTB);
  // h1: (1024 x 36864) @ (36864 x 512), split-K=16, swizzled 512 blocks (mc=4)
  k_mfma<false><<<512, 256, 0, stream>>>(OUTB, 36864, W1T, 36864, (void*)P, 512, 2304, 524288, 4);
  k_reduce_stats<<<128, 256, 0, stream>>>((const float4*)P, (float4*)H1, SUM1, SSQ1);
  k_bngelu<<<512, 256, 0, stream>>>(H1, SUM1, SSQ1, bn1g, bn1b, H1B);
  // h2: (1024 x 512) @ (512 x 256), split-K=4 -> 64 blocks (P reused as partials)
  k_mfma<false><<<dim3(8,2,4), 256, 0, stream>>>(H1B, 512, W2T, 512, (void*)P, 256, 128, 262144, 0);
  k_stats2r<<<32, 256, 0, stream>>>(P, H2, MU2, RS2);
  k_final<<<1024, 256, 0, stream>>>(H2, MU2, RS2, bn2g, bn2b, hc_w3, hc_b3, (float*)d_out);
}

// Round 2
// 883.058 us; speedup vs baseline: 1.0505x; 1.0385x over previous
//
#include <hip/hip_runtime.h>
#include <math.h>

// ---------------------------------------------------------------------------
// Problem constants: B=1024, XDIM=62, TWIN=10, INCH=128, MID=256, OUT=512,
// K=3, K1=10, LIN=512.  REGIONS partition nodes 0..61 exactly once.
// hc_b1/hc_b2 dropped: BN subtracts the batch mean -> bias-invariant.
// Round 2 changes vs 917us:
//  - k_spread2 + k_mfma_region merged into k_mid (one dispatch, LDS union).
//  - cheby2 + cheby1 merged into k_dual (one dispatch, block-id split).
//  - k_reduce_stats + k_bngelu -> k_tail1 (128 co-resident blocks, atomic
//    stats + release/acquire spin). H1 buffer eliminated.
//  - k_stats2r + k_final -> k_tail2 (32 co-resident blocks, same pattern).
//    H2 buffer eliminated.
//  Dispatches 13 -> 9.
// ---------------------------------------------------------------------------

// concat order of nodes (p -> node)
__constant__ int cOrder[62] = {
  0,1,2,3,4,
  5,6,7,14,15,16,
  8,9,10,17,18,19,
  11,12,13,20,21,22,
  23,24,25,32,33,34,
  26,27,28,35,36,37,
  29,30,31,38,39,40,
  41,42,43,50,51,57,
  44,45,46,52,53,54,58,59,60,
  47,48,49,55,56,61
};
// node -> position in concat order
__constant__ int cPos[62] = {
  0,1,2,3,4, 5,6,7, 11,12,13, 17,18,19, 8,9,10, 14,15,16, 20,21,22,
  23,24,25, 29,30,31, 35,36,37, 26,27,28, 32,33,34, 38,39,40,
  41,42,43, 47,48,49, 56,57,58, 44,45, 50,51,52, 59,60, 46, 53,54,55, 61
};
// per-region K (=L*128) and cumulative k offset
__constant__ int cRegK[10]   = {640,768,768,768,768,768,768,768,1152,768};
__constant__ int cRegCum[10] = {0,640,1408,2176,2944,3712,4480,5248,6016,7168};

struct Ptr10 { const float* p[10]; };

typedef __attribute__((ext_vector_type(8))) short bf16x8;
typedef __attribute__((ext_vector_type(4))) float f32x4;

__device__ __forceinline__ float gelu_exact(float v){
  return 0.5f * v * (1.0f + erff(v * 0.70710678118654752f));
}
__device__ __forceinline__ unsigned short f2bf(float f){
  unsigned u = __float_as_uint(f);
  unsigned r = (u + 0x7fffu + ((u >> 16) & 1u)) >> 16;
  return (unsigned short)r;
}
__device__ __forceinline__ float bf2f(unsigned short u){
  return __uint_as_float(((unsigned)u) << 16);
}
__device__ __forceinline__ void load_lds16(const unsigned short* g, unsigned short* l){
  __builtin_amdgcn_global_load_lds(
      (const __attribute__((address_space(1))) void*)g,
      (__attribute__((address_space(3))) void*)l, 16, 0, 0);
}

// ---------------------------------------------------------------------------
// MFMA GEMM: C(MxN) = A(MxK) @ BT(NxK)^T, bf16 in, fp32 acc. 128x128 tile,
// BK=32, XOR-swizzled LDS, global_load_lds w=16.  Used for h1 (split-K 16)
// and h2 (split-K 4), both fp32-partial stores.
// ---------------------------------------------------------------------------
template<bool RELU>
__global__ __launch_bounds__(256) void k_mfma(
    const unsigned short* __restrict__ A, long lda,
    const unsigned short* __restrict__ BT, long ldb,
    void* __restrict__ Cv, int ldc, int kPerZ, long cStrideZ, int mcCount){
  __shared__ unsigned short As[128*32];
  __shared__ unsigned short Bs[128*32];
  int mt, nt, zt;
  if (mcCount){
    int id = blockIdx.x;
    int c = ((id >> 6) << 3) + (id & 7);   // cluster index
    int member = (id >> 3) & 7;
    zt = c / mcCount;
    int mc = c - zt*mcCount;
    mt = mc*2 + (member >> 2);
    nt = member & 3;
  } else { mt = blockIdx.x; nt = blockIdx.y; zt = blockIdx.z; }
  int tid = threadIdx.x;
  int wave = tid >> 6, lane = tid & 63;
  int m0 = mt * 128, n0 = nt * 128;
  int kStart = zt * kPerZ;
  int waveM = wave >> 1, waveN = wave & 1;
  int lr = lane >> 2, ch = lane & 3;
  int quad = lane >> 4, mrow = lane & 15;
  int swe = ((quad ^ (mrow & 3)) << 3);

  int rA0 = wave*32 + lr;
  int rA1 = rA0 + 16;
  int ce  = ((ch ^ (rA0 & 3)) << 3);
  const unsigned short* gA0 = A  + (long)(m0 + rA0)*lda + kStart + ce;
  const unsigned short* gA1 = A  + (long)(m0 + rA1)*lda + kStart + ce;
  const unsigned short* gB0 = BT + (long)(n0 + rA0)*ldb + kStart + ce;
  const unsigned short* gB1 = BT + (long)(n0 + rA1)*ldb + kStart + ce;
  unsigned short* lA0 = &As[(wave*32)*32];
  unsigned short* lA1 = &As[(wave*32+16)*32];
  unsigned short* lB0 = &Bs[(wave*32)*32];
  unsigned short* lB1 = &Bs[(wave*32+16)*32];

  f32x4 acc[4][4] = {};
  int nIter = kPerZ >> 5;
  for (int it = 0; it < nIter; ++it){
    long ko = (long)it << 5;
    load_lds16(gA0 + ko, lA0);
    load_lds16(gA1 + ko, lA1);
    load_lds16(gB0 + ko, lB0);
    load_lds16(gB1 + ko, lB1);
    __syncthreads();
    bf16x8 af[4], bfr[4];
#pragma unroll
    for (int mi = 0; mi < 4; mi++)
      af[mi] = *(const bf16x8*)&As[(waveM*64 + mi*16 + mrow)*32 + swe];
#pragma unroll
    for (int ni = 0; ni < 4; ni++)
      bfr[ni] = *(const bf16x8*)&Bs[(waveN*64 + ni*16 + mrow)*32 + swe];
#pragma unroll
    for (int mi = 0; mi < 4; mi++)
#pragma unroll
      for (int ni = 0; ni < 4; ni++)
        acc[mi][ni] = __builtin_amdgcn_mfma_f32_16x16x32_bf16(
            af[mi], bfr[ni], acc[mi][ni], 0, 0, 0);
    __syncthreads();
  }
  if (RELU){
    unsigned short* C = (unsigned short*)Cv;
#pragma unroll
    for (int mi = 0; mi < 4; mi++)
#pragma unroll
      for (int ni = 0; ni < 4; ni++){
        int col = n0 + waveN*64 + ni*16 + mrow;
#pragma unroll
        for (int r = 0; r < 4; r++){
          int row = m0 + waveM*64 + mi*16 + quad*4 + r;
          C[(long)row*ldc + col] = f2bf(fmaxf(acc[mi][ni][r], 0.f));
        }
      }
  } else {
    float* C = (float*)Cv + (long)zt * cStrideZ;
#pragma unroll
    for (int mi = 0; mi < 4; mi++)
#pragma unroll
      for (int ni = 0; ni < 4; ni++){
        int col = n0 + waveN*64 + ni*16 + mrow;
#pragma unroll
        for (int r = 0; r < 4; r++){
          int row = m0 + waveM*64 + mi*16 + quad*4 + r;
          C[(long)row*ldc + col] = acc[mi][ni][r];
        }
      }
  }
}
template __global__ void k_mfma<true>(const unsigned short*, long, const unsigned short*, long, void*, int, int, long, int);
template __global__ void k_mfma<false>(const unsigned short*, long, const unsigned short*, long, void*, int, int, long, int);

// ---------------------------------------------------------------------------
// k_dual: cheby2 (blocks [0,320)) + cheby1 (blocks [320,2304)) in one
// dispatch.  Both are bf16 GEMM + relu store, 128x128 tile, zt=0.
//   cheby2: (10240 x 768) @ (768 x 512)^T  mc=40
//   cheby1: (63488 x 384) @ (384 x 512)^T  mc=248
// ---------------------------------------------------------------------------
__global__ __launch_bounds__(256) void k_dual(
    const unsigned short* __restrict__ A2c, const unsigned short* __restrict__ B2c,
    unsigned short* __restrict__ C2c,
    const unsigned short* __restrict__ A1c, const unsigned short* __restrict__ B1c,
    unsigned short* __restrict__ C1c){
  __shared__ unsigned short As[128*32];
  __shared__ unsigned short Bs[128*32];
  int id = blockIdx.x;
  bool is1 = id >= 320;
  const unsigned short* A  = is1 ? A1c : A2c;
  const unsigned short* BT = is1 ? B1c : B2c;
  unsigned short* C = is1 ? C1c : C2c;
  long lda = is1 ? 384 : 768;
  long ldb = lda;
  int kPerZ = (int)lda;
  if (is1) id -= 320;
  int c = ((id >> 6) << 3) + (id & 7);
  int member = (id >> 3) & 7;
  int mt = c*2 + (member >> 2);
  int nt = member & 3;
  int tid = threadIdx.x;
  int wave = tid >> 6, lane = tid & 63;
  int m0 = mt * 128, n0 = nt * 128;
  int waveM = wave >> 1, waveN = wave & 1;
  int lr = lane >> 2, ch = lane & 3;
  int quad = lane >> 4, mrow = lane & 15;
  int swe = ((quad ^ (mrow & 3)) << 3);

  int rA0 = wave*32 + lr;
  int rA1 = rA0 + 16;
  int ce  = ((ch ^ (rA0 & 3)) << 3);
  const unsigned short* gA0 = A  + (long)(m0 + rA0)*lda + ce;
  const unsigned short* gA1 = A  + (long)(m0 + rA1)*lda + ce;
  const unsigned short* gB0 = BT + (long)(n0 + rA0)*ldb + ce;
  const unsigned short* gB1 = BT + (long)(n0 + rA1)*ldb + ce;
  unsigned short* lA0 = &As[(wave*32)*32];
  unsigned short* lA1 = &As[(wave*32+16)*32];
  unsigned short* lB0 = &Bs[(wave*32)*32];
  unsigned short* lB1 = &Bs[(wave*32+16)*32];

  f32x4 acc[4][4] = {};
  int nIter = kPerZ >> 5;
  for (int it = 0; it < nIter; ++it){
    long ko = (long)it << 5;
    load_lds16(gA0 + ko, lA0);
    load_lds16(gA1 + ko, lA1);
    load_lds16(gB0 + ko, lB0);
    load_lds16(gB1 + ko, lB1);
    __syncthreads();
    bf16x8 af[4], bfr[4];
#pragma unroll
    for (int mi = 0; mi < 4; mi++)
      af[mi] = *(const bf16x8*)&As[(waveM*64 + mi*16 + mrow)*32 + swe];
#pragma unroll
    for (int ni = 0; ni < 4; ni++)
      bfr[ni] = *(const bf16x8*)&Bs[(waveN*64 + ni*16 + mrow)*32 + swe];
#pragma unroll
    for (int mi = 0; mi < 4; mi++)
#pragma unroll
      for (int ni = 0; ni < 4; ni++)
        acc[mi][ni] = __builtin_amdgcn_mfma_f32_16x16x32_bf16(
            af[mi], bfr[ni], acc[mi][ni], 0, 0, 0);
    __syncthreads();
  }
#pragma unroll
  for (int mi = 0; mi < 4; mi++)
#pragma unroll
    for (int ni = 0; ni < 4; ni++){
      int col = n0 + waveN*64 + ni*16 + mrow;
#pragma unroll
      for (int r = 0; r < 4; r++){
        int row = m0 + waveM*64 + mi*16 + quad*4 + r;
        C[(long)row*512 + col] = f2bf(fmaxf(acc[mi][ni][r], 0.f));
      }
    }
}

// ---------------------------------------------------------------------------
// k_mid: blocks [0,1024) = spread2 (XCAT slots 1,2); blocks [1024,1184) =
// region MFMA GEMM (g2in).  Both depend only on ARb; independent of each
// other.  LDS union: spread2 needs 31744 B, region needs 16384 B.
// ---------------------------------------------------------------------------
__global__ __launch_bounds__(256) void k_mid(
    const unsigned short* __restrict__ ARb, const float* __restrict__ AT,
    const float* __restrict__ A2T, unsigned short* __restrict__ xcat,
    const unsigned short* __restrict__ RWT, const float* __restrict__ regb,
    float* __restrict__ g2in){
  __shared__ __align__(16) char smraw[32768];
  int id = blockIdx.x;
  int tid = threadIdx.x;
  if (id < 1024){
    // ---- spread2: XCAT slot1 = bf16(A @ g_b), slot2 = bf16(A^2 @ g_b) ----
    float* sgn = (float*)smraw;
    int b = id;
    for (int i = tid; i < 7936; i += 256){
      int p = i >> 7, c = i & 127;
      sgn[cOrder[p]*128 + c] = bf2f(ARb[(long)b*7936 + i]);
    }
    __syncthreads();
    int c = tid & 127, mat = tid >> 7;      // mat uniform per wave
    const float* MT = mat ? A2T : AT;
    float acc[62];
#pragma unroll
    for (int n = 0; n < 62; n++) acc[n] = 0.f;
    for (int m = 0; m < 62; m++){
      float gv = sgn[m*128 + c];
      const float* Mp = MT + m*62;          // contiguous row -> scalar loads
#pragma unroll
      for (int n = 0; n < 62; n++) acc[n] = fmaf(Mp[n], gv, acc[n]);
    }
    long base = (long)b*23808 + (mat+1)*128 + c;
#pragma unroll
    for (int n = 0; n < 62; n++) xcat[base + (long)n*384] = f2bf(acc[n]);
    return;
  }
  // ---- region GEMM: g2in[b, z*256+m] = ARb[b, cum_z:]*RWT_z^T + regb ----
  unsigned short* As = (unsigned short*)smraw;          // 128*32 shorts
  unsigned short* Bs = As + 128*32;                     // 128*32 shorts
  int id2 = id - 1024;
  int z = id2 >> 4;
  int m  = id2 & 15;
  int mt = m >> 1, nt = m & 1;
  int K = cRegK[z];
  int cumk = cRegCum[z];
  const unsigned short* A  = ARb + cumk;
  const unsigned short* BT = RWT + (long)cumk*256;
  long lda = 7936, ldb = K;
  int wave = tid >> 6, lane = tid & 63;
  int m0 = mt * 128, n0 = nt * 128;
  int waveM = wave >> 1, waveN = wave & 1;
  int lr = lane >> 2, ch = lane & 3;
  int quad = lane >> 4, mrow = lane & 15;
  int swe = ((quad ^ (mrow & 3)) << 3);

  int rA0 = wave*32 + lr;
  int rA1 = rA0 + 16;
  int ce  = ((ch ^ (rA0 & 3)) << 3);
  const unsigned short* gA0 = A  + (long)(m0 + rA0)*lda + ce;
  const unsigned short* gA1 = A  + (long)(m0 + rA1)*lda + ce;
  const unsigned short* gB0 = BT + (long)(n0 + rA0)*ldb + ce;
  const unsigned short* gB1 = BT + (long)(n0 + rA1)*ldb + ce;
  unsigned short* lA0 = &As[(wave*32)*32];
  unsigned short* lA1 = &As[(wave*32+16)*32];
  unsigned short* lB0 = &Bs[(wave*32)*32];
  unsigned short* lB1 = &Bs[(wave*32+16)*32];

  f32x4 acc[4][4] = {};
  int nIter = K >> 5;
  for (int it = 0; it < nIter; ++it){
    long ko = (long)it << 5;
    load_lds16(gA0 + ko, lA0);
    load_lds16(gA1 + ko, lA1);
    load_lds16(gB0 + ko, lB0);
    load_lds16(gB1 + ko, lB1);
    __syncthreads();
    bf16x8 af[4], bfr[4];
#pragma unroll
    for (int mi = 0; mi < 4; mi++)
      af[mi] = *(const bf16x8*)&As[(waveM*64 + mi*16 + mrow)*32 + swe];
#pragma unroll
    for (int ni = 0; ni < 4; ni++)
      bfr[ni] = *(const bf16x8*)&Bs[(waveN*64 + ni*16 + mrow)*32 + swe];
#pragma unroll
    for (int mi = 0; mi < 4; mi++)
#pragma unroll
      for (int ni = 0; ni < 4; ni++)
        acc[mi][ni] = __builtin_amdgcn_mfma_f32_16x16x32_bf16(
            af[mi], bfr[ni], acc[mi][ni], 0, 0, 0);
    __syncthreads();
  }
#pragma unroll
  for (int mi = 0; mi < 4; mi++)
#pragma unroll
    for (int ni = 0; ni < 4; ni++){
      int col = n0 + waveN*64 + ni*16 + mrow;
      float bias = regb[z*256 + col];
#pragma unroll
      for (int r = 0; r < 4; r++){
        int row = m0 + waveM*64 + mi*16 + quad*4 + r;
        g2in[(long)row*2560 + z*256 + col] = acc[mi][ni][r] + bias;
      }
    }
}

// ---------------------------------------------------------------------------
// k_front: one dispatch for all input-only work.
//   [0,4784)        : 64x64 fp32->bf16 transpose tiles (hc_w1/hc_w2/ch1w/ch2w)
//   [4784,7344)     : region-weight transpose
//   [7344,7406)     : A-transpose + (A@A)^T
//   [7406,15342)    : g-kernel, 8 (b,n) rows/block, float4 channel loads
//   [15342,15344)   : zero bn stat accumulators + spin counters (2048 floats)
// ---------------------------------------------------------------------------
__global__ __launch_bounds__(256) void k_front(
    const float* __restrict__ s0, unsigned short* __restrict__ d0,
    const float* __restrict__ s1, unsigned short* __restrict__ d1,
    const float* __restrict__ s2, unsigned short* __restrict__ d2,
    const float* __restrict__ s3, unsigned short* __restrict__ d3,
    Ptr10 rws, unsigned short* __restrict__ RWT,
    const float* __restrict__ Amat, float* __restrict__ AT,
    float* __restrict__ A2T,
    const float* __restrict__ x, const float* __restrict__ tw,
    const float* __restrict__ tb, unsigned short* __restrict__ arb,
    unsigned short* __restrict__ xcat, float* __restrict__ sumz){
  __shared__ float smem[64*65];
  int id = blockIdx.x;
  int tid = threadIdx.x;
  if (id >= 15342){
    *(float4*)(sumz + (id-15342)*1024 + tid*4) = make_float4(0.f,0.f,0.f,0.f);
    return;
  }
  if (id >= 7406){
    // g[b,n,c] = (sum_i x*tfe_w + tfe_b) * exp(-var_i(x)) (ddof=1), bf16 out
    int q = id - 7406;
    int r = tid >> 5, j = tid & 31;        // 8 rows x 32 lanes, 4 ch/lane
    int idx = q*8 + r;                      // b*62+n
    int b = idx / 62, n = idx - b*62;
    const float4* xp = (const float4*)(x + (long)idx*1280) + j;
    float sx=0.f,sy=0.f,sz=0.f,sw=0.f;
    float qx=0.f,qy=0.f,qz=0.f,qw=0.f;
    float gx=0.f,gy=0.f,gz=0.f,gw=0.f;
#pragma unroll
    for (int i = 0; i < 10; i++){
      float4 v = xp[i*32];
      float w = tw[n*10+i];
      sx+=v.x; sy+=v.y; sz+=v.z; sw+=v.w;
      qx=fmaf(v.x,v.x,qx); qy=fmaf(v.y,v.y,qy);
      qz=fmaf(v.z,v.z,qz); qw=fmaf(v.w,v.w,qw);
      gx=fmaf(v.x,w,gx); gy=fmaf(v.y,w,gy);
      gz=fmaf(v.z,w,gz); gw=fmaf(v.w,w,gw);
    }
    float tbn = tb[n];
    float mx_=sx*0.1f, my_=sy*0.1f, mz_=sz*0.1f, mw_=sw*0.1f;
    float rx = (gx+tbn)*expf(-(qx-10.f*mx_*mx_)*(1.f/9.f));
    float ry = (gy+tbn)*expf(-(qy-10.f*my_*my_)*(1.f/9.f));
    float rz = (gz+tbn)*expf(-(qz-10.f*mz_*mz_)*(1.f/9.f));
    float rw = (gw+tbn)*expf(-(qw-10.f*mw_*mw_)*(1.f/9.f));
    ushort4 u = make_ushort4(f2bf(rx), f2bf(ry), f2bf(rz), f2bf(rw));
    *(ushort4*)(arb  + (long)b*7936  + cPos[n]*128 + j*4) = u;
    *(ushort4*)(xcat + (long)b*23808 + n*384       + j*4) = u;
    return;
  }
  if (id < 7344 && id >= 4784){
    // region-weight transpose: RWT[cum+m*K + l*128+c] = bf16(rw[m][c*L+l])
    int q = id - 4784;
    int z = q >> 8, m = q & 255;
    int K = cRegK[z], L = K >> 7;
    const float* rw = rws.p[z] + (long)m*K;
    unsigned short* dst = RWT + (long)cRegCum[z]*256 + (long)m*K;
    for (int i = tid; i < K; i += 256) smem[i] = rw[i];
    __syncthreads();
    for (int k = tid; k < K; k += 256){
      int l = k >> 7, c = k & 127;
      dst[k] = f2bf(smem[c*L + l]);
    }
    return;
  }
  if (id >= 7344){
    // A helpers, one row per block
    int r = id - 7344, c = tid;
    if (c < 62) smem[c] = Amat[r*62 + c];
    __syncthreads();
    if (c < 62){
      AT[c*62 + r] = smem[c];
      float s = 0.f;
      for (int t = 0; t < 62; t++) s = fmaf(smem[t], Amat[t*62 + c], s);
      A2T[c*62 + r] = s;
    }
    return;
  }
  // 64x64 fp32->bf16 transpose tiles
  const float* src; unsigned short* dst; int R, C, rt, ct;
  if (id < 4608){ src=s0; dst=d0; R=36864; C=512; rt=id>>3;  ct=id&7; }
  else if (id < 4640){ int q=id-4608; src=s1; dst=d1; R=512; C=256; rt=q>>2; ct=q&3; }
  else if (id < 4688){ int q=id-4640; src=s2; dst=d2; R=384; C=512; rt=q>>3; ct=q&7; }
  else { int q=id-4688; src=s3; dst=d3; R=768; C=512; rt=q>>3; ct=q&7; }
  int r0 = rt*64, c0 = ct*64;
  int rr = tid >> 2, cb = (tid & 3) << 2;
#pragma unroll
  for (int i = 0; i < 4; i++){
    int cc = cb + i*16;
    float4 v = *(const float4*)(src + (long)(r0+rr)*C + c0 + cc);
    smem[rr*65+cc+0]=v.x; smem[rr*65+cc+1]=v.y;
    smem[rr*65+cc+2]=v.z; smem[rr*65+cc+3]=v.w;
  }
  __syncthreads();
  int cc = tid >> 2, rb = (tid & 3) << 2;
#pragma unroll
  for (int i = 0; i < 4; i++){
    int r = rb + i*16;
    ushort4 u = make_ushort4(f2bf(smem[(r+0)*65+cc]), f2bf(smem[(r+1)*65+cc]),
                             f2bf(smem[(r+2)*65+cc]), f2bf(smem[(r+3)*65+cc]));
    *(ushort4*)(dst + (long)(c0+cc)*R + r0 + r) = u;
  }
}

// ---------------------------------------------------------------------------
// 4) X2cat[b, n, k*256+t] = (A1^k @ g2in[b])[n,t], k=0..2  (bf16 out)
// ---------------------------------------------------------------------------
__global__ __launch_bounds__(256) void k_x2cat(
    const float* __restrict__ g2in, const float* __restrict__ A1,
    unsigned short* __restrict__ X2){
  __shared__ float sg[2560];
  __shared__ float sA1[100];
  __shared__ float sA2[100];
  int b = blockIdx.x, tid = threadIdx.x;
  for (int i = tid; i < 2560; i += 256) sg[i] = g2in[(long)b*2560 + i];
  if (tid < 100) sA1[tid] = A1[tid];
  __syncthreads();
  if (tid < 100){
    int n = tid/10, m = tid - n*10;
    float a = 0.f;
#pragma unroll
    for (int t = 0; t < 10; t++) a = fmaf(sA1[n*10+t], sA1[t*10+m], a);
    sA2[tid] = a;
  }
  __syncthreads();
  for (int i = tid; i < 2560; i += 256){
    int n = i >> 8, t = i & 255;
    float v1 = 0.f, v2 = 0.f;
#pragma unroll
    for (int m = 0; m < 10; m++){
      float gv = sg[(m<<8) + t];
      v1 = fmaf(sA1[n*10+m], gv, v1);
      v2 = fmaf(sA2[n*10+m], gv, v2);
    }
    long base = (long)b*7680 + n*768;
    X2[base + t]       = f2bf(sg[i]);
    X2[base + 256 + t] = f2bf(v1);
    X2[base + 512 + t] = f2bf(v2);
  }
}

// ---------------------------------------------------------------------------
// 6) softmax-gated concat, all per-thread state in registers (no LDS).
//    grid (1024, 2) x 256 thr; thread owns one (b, o) column.
// ---------------------------------------------------------------------------
__global__ __launch_bounds__(256) void k_softcat(
    const unsigned short* __restrict__ g1, const unsigned short* __restrict__ g2,
    const float* __restrict__ bg_, const float* __restrict__ cg_,
    unsigned short* __restrict__ outb){
  int b = blockIdx.x;
  int o = blockIdx.y*256 + threadIdx.x;
  float v[72];
  const unsigned short* p1 = g1 + (long)b*62*512 + o;
#pragma unroll
  for (int j = 0; j < 62; j++) v[j] = bf2f(p1[j*512]);
  const unsigned short* p2 = g2 + (long)b*10*512 + o;
#pragma unroll
  for (int j = 0; j < 10; j++) v[62+j] = bf2f(p2[j*512]);
  float bg = *bg_, cg = *cg_;
  float mx = -1e30f;
#pragma unroll
  for (int j = 0; j < 72; j++){
    float av = (j < 62 ? bg : cg) * v[j];
    mx = fmaxf(mx, av);
  }
  float sum = 0.f;
#pragma unroll
  for (int j = 0; j < 72; j++){
    float e = expf((j < 62 ? bg : cg) * v[j] - mx);
    sum += e;
    v[j] = e * v[j];
  }
  float inv = 1.f / sum;
  unsigned short* op = outb + (long)b*36864 + o;
#pragma unroll
  for (int j = 0; j < 72; j++) op[j*512] = f2bf(v[j] * inv);
}

// ---------------------------------------------------------------------------
// k_tail1: 128 co-resident blocks.  Phase A: reduce 16 split-K partials
// (block = 8 rows x 512 cols, values kept in registers), accumulate column
// sum/sumsq via fp32 atomics.  Spin on release/acquire counter until all
// 128 blocks done.  Phase B: finalize mu/rs, bn1+gelu, write H1B bf16.
// H1 never materialized.
// ---------------------------------------------------------------------------
__global__ __launch_bounds__(256) void k_tail1(
    const float4* __restrict__ P, const float* __restrict__ gam,
    const float* __restrict__ bet, float* __restrict__ sum,
    float* __restrict__ ssq, unsigned int* __restrict__ cnt,
    unsigned short* __restrict__ h1b){
  __shared__ float4 ls[128], ls2[128];
  int tid = threadIdx.x;
  int c  = tid & 127;        // float4-column
  int rr = tid >> 7;         // 0/1
  int r0 = blockIdx.x * 8;
  float4 va[4];
  float4 s1 = make_float4(0.f,0.f,0.f,0.f);
  float4 s2 = make_float4(0.f,0.f,0.f,0.f);
#pragma unroll
  for (int k = 0; k < 4; k++){
    int row = r0 + rr + 2*k;
    long idx = (long)row*128 + c;
    float4 v = make_float4(0.f,0.f,0.f,0.f);
#pragma unroll
    for (int s = 0; s < 16; s++){
      float4 p = P[(long)s*131072 + idx];
      v.x += p.x; v.y += p.y; v.z += p.z; v.w += p.w;
    }
    va[k] = v;
    s1.x += v.x; s1.y += v.y; s1.z += v.z; s1.w += v.w;
    s2.x = fmaf(v.x,v.x,s2.x); s2.y = fmaf(v.y,v.y,s2.y);
    s2.z = fmaf(v.z,v.z,s2.z); s2.w = fmaf(v.w,v.w,s2.w);
  }
  if (rr){ ls[c] = s1; ls2[c] = s2; }
  __syncthreads();
  if (!rr){
    float4 o1 = ls[c], o2 = ls2[c];
    atomicAdd(&sum[c*4+0], s1.x+o1.x); atomicAdd(&sum[c*4+1], s1.y+o1.y);
    atomicAdd(&sum[c*4+2], s1.z+o1.z); atomicAdd(&sum[c*4+3], s1.w+o1.w);
    atomicAdd(&ssq[c*4+0], s2.x+o2.x); atomicAdd(&ssq[c*4+1], s2.y+o2.y);
    atomicAdd(&ssq[c*4+2], s2.z+o2.z); atomicAdd(&ssq[c*4+3], s2.w+o2.w);
  }
  __threadfence();
  __syncthreads();
  if (tid == 0){
    __hip_atomic_fetch_add(cnt, 1u, __ATOMIC_RELEASE, __HIP_MEMORY_SCOPE_AGENT);
    while (__hip_atomic_load(cnt, __ATOMIC_ACQUIRE, __HIP_MEMORY_SCOPE_AGENT) < 128u)
      __builtin_amdgcn_s_sleep(16);
  }
  __syncthreads();
  int j = c*4;
  float mu0 = __hip_atomic_load(&sum[j+0], __ATOMIC_RELAXED, __HIP_MEMORY_SCOPE_AGENT)*(1.f/1024.f);
  float mu1 = __hip_atomic_load(&sum[j+1], __ATOMIC_RELAXED, __HIP_MEMORY_SCOPE_AGENT)*(1.f/1024.f);
  float mu2 = __hip_atomic_load(&sum[j+2], __ATOMIC_RELAXED, __HIP_MEMORY_SCOPE_AGENT)*(1.f/1024.f);
  float mu3 = __hip_atomic_load(&sum[j+3], __ATOMIC_RELAXED, __HIP_MEMORY_SCOPE_AGENT)*(1.f/1024.f);
  float q0 = __hip_atomic_load(&ssq[j+0], __ATOMIC_RELAXED, __HIP_MEMORY_SCOPE_AGENT);
  float q1 = __hip_atomic_load(&ssq[j+1], __ATOMIC_RELAXED, __HIP_MEMORY_SCOPE_AGENT);
  float q2 = __hip_atomic_load(&ssq[j+2], __ATOMIC_RELAXED, __HIP_MEMORY_SCOPE_AGENT);
  float q3 = __hip_atomic_load(&ssq[j+3], __ATOMIC_RELAXED, __HIP_MEMORY_SCOPE_AGENT);
  float rs0 = rsqrtf(q0*(1.f/1024.f) - mu0*mu0 + 1e-5f);
  float rs1 = rsqrtf(q1*(1.f/1024.f) - mu1*mu1 + 1e-5f);
  float rs2 = rsqrtf(q2*(1.f/1024.f) - mu2*mu2 + 1e-5f);
  float rs3 = rsqrtf(q3*(1.f/1024.f) - mu3*mu3 + 1e-5f);
  float g0 = gam[j+0], g1 = gam[j+1], g2 = gam[j+2], g3 = gam[j+3];
  float b0 = bet[j+0], b1 = bet[j+1], b2 = bet[j+2], b3 = bet[j+3];
#pragma unroll
  for (int k = 0; k < 4; k++){
    int row = r0 + rr + 2*k;
    float4 v = va[k];
    ushort4 u;
    u.x = f2bf(gelu_exact((v.x - mu0)*rs0*g0 + b0));
    u.y = f2bf(gelu_exact((v.y - mu1)*rs1*g1 + b1));
    u.z = f2bf(gelu_exact((v.z - mu2)*rs2*g2 + b2));
    u.w = f2bf(gelu_exact((v.w - mu3)*rs3*g3 + b3));
    *(ushort4*)(h1b + (long)row*512 + j) = u;
  }
}

// ---------------------------------------------------------------------------
// k_tail2: 32 co-resident blocks.  Block owns 32 rows x 256 cols.
// Phase A: reduce 4 split-K h2 partials into registers, atomic col stats.
// Spin.  Phase B: bn2+gelu, dot with hc_w3 (+b3), softmax over 4, write out.
// H2 never materialized.
// ---------------------------------------------------------------------------
__global__ __launch_bounds__(256) void k_tail2(
    const float* __restrict__ P2, const float* __restrict__ gam,
    const float* __restrict__ bet, const float* __restrict__ w3,
    const float* __restrict__ b3, float* __restrict__ sum,
    float* __restrict__ ssq, unsigned int* __restrict__ cnt,
    float* __restrict__ outp){
  __shared__ float lv[32][257];
  __shared__ float rd[32][8][4];
  int tid = threadIdx.x;          // col 0..255
  int rbase = blockIdx.x * 32;
  float v[32];
  float s = 0.f, s2 = 0.f;
#pragma unroll 8
  for (int r = 0; r < 32; r++){
    int row = rbase + r;
    float a = 0.f;
#pragma unroll
    for (int sp = 0; sp < 4; sp++)
      a += P2[((long)sp*1024 + row)*256 + tid];
    v[r] = a;
    s += a; s2 = fmaf(a, a, s2);
  }
  atomicAdd(&sum[tid], s);
  atomicAdd(&ssq[tid], s2);
  __threadfence();
  __syncthreads();
  if (tid == 0){
    __hip_atomic_fetch_add(cnt, 1u, __ATOMIC_RELEASE, __HIP_MEMORY_SCOPE_AGENT);
    while (__hip_atomic_load(cnt, __ATOMIC_ACQUIRE, __HIP_MEMORY_SCOPE_AGENT) < 32u)
      __builtin_amdgcn_s_sleep(16);
  }
  __syncthreads();
  float mu = __hip_atomic_load(&sum[tid], __ATOMIC_RELAXED, __HIP_MEMORY_SCOPE_AGENT)*(1.f/1024.f);
  float qq = __hip_atomic_load(&ssq[tid], __ATOMIC_RELAXED, __HIP_MEMORY_SCOPE_AGENT);
  float rs = rsqrtf(qq*(1.f/1024.f) - mu*mu + 1e-5f);
  float gm = gam[tid], bt = bet[tid];
#pragma unroll 8
  for (int r = 0; r < 32; r++)
    lv[r][tid] = gelu_exact((v[r] - mu)*rs*gm + bt);
  __syncthreads();
  // per-row dot with w3: thread = (row = tid>>3, seg = tid&7)
  int row = tid >> 3, seg = tid & 7;
  float p0=0.f,p1=0.f,p2=0.f,p3=0.f;
#pragma unroll
  for (int i = 0; i < 32; i++){
    int cc = seg*32 + i;
    float a = lv[row][cc];
    float4 w = ((const float4*)w3)[cc];
    p0 = fmaf(a, w.x, p0); p1 = fmaf(a, w.y, p1);
    p2 = fmaf(a, w.z, p2); p3 = fmaf(a, w.w, p3);
  }
  rd[row][seg][0]=p0; rd[row][seg][1]=p1; rd[row][seg][2]=p2; rd[row][seg][3]=p3;
  __syncthreads();
  if (tid < 32){
    float l[4];
#pragma unroll
    for (int c = 0; c < 4; c++){
      float a = 0.f;
#pragma unroll
      for (int g = 0; g < 8; g++) a += rd[tid][g][c];
      l[c] = a + b3[c];
    }
    float m = fmaxf(fmaxf(l[0], l[1]), fmaxf(l[2], l[3]));
    float e[4]; float su = 0.f;
#pragma unroll
    for (int c = 0; c < 4; c++){ e[c] = expf(l[c]-m); su += e[c]; }
    float inv = 1.f / su;
#pragma unroll
    for (int c = 0; c < 4; c++) outp[(long)(rbase+tid)*4 + c] = e[c]*inv;
  }
}

// ---------------------------------------------------------------------------
// Workspace layout (byte offsets), peak ~248 MB.
// Stats block @246415360 (8 KB, zeroed by k_front):
//   SUM1[512] SSQ1[512] SUM2[256] SSQ2[256] CNT1 CNT2 pad
// ---------------------------------------------------------------------------
extern "C" void kernel_launch(void* const* d_in, const int* in_sizes, int n_in,
                              void* d_out, int out_size, void* d_ws, size_t ws_size,
                              hipStream_t stream){
  (void)n_in; (void)out_size; (void)ws_size;
  bool dictOrder = (in_sizes[9] == 2560);
  const float* x     = (const float*)d_in[0];
  const float* tfe_w = (const float*)d_in[1];
  const float* tfe_b = (const float*)d_in[2];
  const float* ch1w  = (const float*)d_in[3];
  const float* Amat  = (const float*)d_in[4];
  const float* ch2w  = (const float*)d_in[5];
  const float* A1mat = (const float*)d_in[6];
  const float* bgate = (const float*)d_in[7];
  const float* cgate = (const float*)d_in[8];
  const float* regb  = (const float*)d_in[dictOrder ? 9 : 19];
  int o = dictOrder ? 0 : 10;
  const float* hc_w1 = (const float*)d_in[10+o];
  const float* bn1g  = (const float*)d_in[12+o];
  const float* bn1b  = (const float*)d_in[13+o];
  const float* hc_w2 = (const float*)d_in[14+o];
  const float* bn2g  = (const float*)d_in[16+o];
  const float* bn2b  = (const float*)d_in[17+o];
  const float* hc_w3 = (const float*)d_in[18+o];
  const float* hc_b3 = (const float*)d_in[19+o];
  Ptr10 rws;
  for (int i = 0; i < 10; i++) rws.p[i] = (const float*)d_in[(dictOrder ? 20 : 9) + i];

  char* Wb = (char*)d_ws;
  unsigned short* ARb   = (unsigned short*)(Wb + 0);
  unsigned short* XCAT  = (unsigned short*)(Wb + 16252928);
  unsigned short* RWT   = (unsigned short*)(Wb + 65011712);
  float*          G2IN  = (float*)(Wb + 69074944);
  unsigned short* X2CAT = (unsigned short*)(Wb + 79560704);
  unsigned short* W1T   = (unsigned short*)(Wb + 95289344);
  unsigned short* WC1T  = (unsigned short*)(Wb + 133038080);
  unsigned short* WC2T  = (unsigned short*)(Wb + 133431296);
  unsigned short* G1    = (unsigned short*)(Wb + 134217728);
  unsigned short* G2    = (unsigned short*)(Wb + 199229440);
  unsigned short* OUTB  = (unsigned short*)(Wb + 0);
  float*          P     = (float*)(Wb + 209715200);
  float*          SUM1  = (float*)(Wb + 246415360);   // stats block (8 KB)
  float*          SSQ1  = SUM1 + 512;
  float*          SUM2  = SUM1 + 1024;
  float*          SSQ2  = SUM1 + 1280;
  unsigned int*   CNT1  = (unsigned int*)(SUM1 + 1536);
  unsigned int*   CNT2  = (unsigned int*)(SUM1 + 1537);
  float*          AT    = (float*)(Wb + 246423552);
  float*          A2T   = (float*)(Wb + 246439040);
  unsigned short* W2T   = (unsigned short*)(Wb + 246454528);
  unsigned short* H1B   = (unsigned short*)(Wb + 246716928);

  // 1) prep transforms + g + stats-block zeroing
  k_front<<<15344, 256, 0, stream>>>(hc_w1, W1T, hc_w2, W2T, ch1w, WC1T,
                                     ch2w, WC2T, rws, RWT, Amat, AT, A2T,
                                     x, tfe_w, tfe_b, ARb, XCAT, SUM1);
  // 2) spread2 (1024 blocks) + region GEMM (160 blocks), one dispatch
  k_mid<<<1184, 256, 0, stream>>>(ARb, AT, A2T, XCAT, RWT, regb, G2IN);
  // 3) A1-hop concat
  k_x2cat<<<1024, 256, 0, stream>>>(G2IN, A1mat, X2CAT);
  // 4) cheby2 (320 blocks) + cheby1 (1984 blocks), one dispatch
  k_dual<<<2304, 256, 0, stream>>>(X2CAT, WC2T, G2, XCAT, WC1T, G1);
  // 5) softmax-gated concat
  k_softcat<<<dim3(1024,2), 256, 0, stream>>>(G1, G2, bgate, cgate, OUTB);
  // 6) h1: (1024 x 36864) @ (36864 x 512), split-K=16, swizzled 512 blocks
  k_mfma<false><<<512, 256, 0, stream>>>(OUTB, 36864, W1T, 36864, (void*)P, 512, 2304, 524288, 4);
  // 7) fused reduce + bn1 stats + gelu -> H1B
  k_tail1<<<128, 256, 0, stream>>>((const float4*)P, bn1g, bn1b, SUM1, SSQ1, CNT1, H1B);
  // 8) h2: (1024 x 512) @ (512 x 256), split-K=4 (P reused as partials)
  k_mfma<false><<<dim3(8,2,4), 256, 0, stream>>>(H1B, 512, W2T, 512, (void*)P, 256, 128, 262144, 0);
  // 9) fused reduce + bn2 + gelu + w3 dot + softmax -> out
  k_tail2<<<32, 256, 0, stream>>>(P, bn2g, bn2b, hc_w3, hc_b3, SUM2, SSQ2, CNT2, (float*)d_out);
}

// Round 4
// 811.935 us; speedup vs baseline: 1.1426x; 1.0876x over previous
//
#include <hip/hip_runtime.h>
#include <math.h>

// ---------------------------------------------------------------------------
// Problem constants: B=1024, XDIM=62, TWIN=10, INCH=128, MID=256, OUT=512,
// K=3, K1=10, LIN=512.  REGIONS partition nodes 0..61 exactly once.
// hc_b1/hc_b2 dropped: BN subtracts the batch mean -> bias-invariant.
// Round 4 = Round 3 resubmit (infra failure, no result last round):
//  - spread2 (A@g, A^2@g) converted from per-thread VALU (62x62 fma/thread,
//    ~2 GFLOP scalar) to per-b MFMA micro-GEMM (64x128x64 padded, 2 k-steps,
//    4 waves = {matrix} x {c-half}).  k_front now emits bf16 row-major A and
//    A@A (64x64 zero-padded) instead of fp32 AT/A2T.
// ---------------------------------------------------------------------------

// concat order of nodes (p -> node)
__constant__ int cOrder[62] = {
  0,1,2,3,4,
  5,6,7,14,15,16,
  8,9,10,17,18,19,
  11,12,13,20,21,22,
  23,24,25,32,33,34,
  26,27,28,35,36,37,
  29,30,31,38,39,40,
  41,42,43,50,51,57,
  44,45,46,52,53,54,58,59,60,
  47,48,49,55,56,61
};
// node -> position in concat order
__constant__ int cPos[62] = {
  0,1,2,3,4, 5,6,7, 11,12,13, 17,18,19, 8,9,10, 14,15,16, 20,21,22,
  23,24,25, 29,30,31, 35,36,37, 26,27,28, 32,33,34, 38,39,40,
  41,42,43, 47,48,49, 56,57,58, 44,45, 50,51,52, 59,60, 46, 53,54,55, 61
};
// per-region K (=L*128) and cumulative k offset
__constant__ int cRegK[10]   = {640,768,768,768,768,768,768,768,1152,768};
__constant__ int cRegCum[10] = {0,640,1408,2176,2944,3712,4480,5248,6016,7168};

struct Ptr10 { const float* p[10]; };

typedef __attribute__((ext_vector_type(8))) short bf16x8;
typedef __attribute__((ext_vector_type(4))) float f32x4;

__device__ __forceinline__ float gelu_exact(float v){
  return 0.5f * v * (1.0f + erff(v * 0.70710678118654752f));
}
__device__ __forceinline__ unsigned short f2bf(float f){
  unsigned u = __float_as_uint(f);
  unsigned r = (u + 0x7fffu + ((u >> 16) & 1u)) >> 16;
  return (unsigned short)r;
}
__device__ __forceinline__ float bf2f(unsigned short u){
  return __uint_as_float(((unsigned)u) << 16);
}
__device__ __forceinline__ void load_lds16(const unsigned short* g, unsigned short* l){
  __builtin_amdgcn_global_load_lds(
      (const __attribute__((address_space(1))) void*)g,
      (__attribute__((address_space(3))) void*)l, 16, 0, 0);
}

// ---------------------------------------------------------------------------
// MFMA GEMM: C(MxN) = A(MxK) @ BT(NxK)^T, bf16 in, fp32 acc. 128x128 tile,
// BK=32, XOR-swizzled LDS, global_load_lds w=16.  Used for h1 (split-K 16)
// and h2 (split-K 4), both fp32-partial stores.
// ---------------------------------------------------------------------------
template<bool RELU>
__global__ __launch_bounds__(256) void k_mfma(
    const unsigned short* __restrict__ A, long lda,
    const unsigned short* __restrict__ BT, long ldb,
    void* __restrict__ Cv, int ldc, int kPerZ, long cStrideZ, int mcCount){
  __shared__ unsigned short As[128*32];
  __shared__ unsigned short Bs[128*32];
  int mt, nt, zt;
  if (mcCount){
    int id = blockIdx.x;
    int c = ((id >> 6) << 3) + (id & 7);   // cluster index
    int member = (id >> 3) & 7;
    zt = c / mcCount;
    int mc = c - zt*mcCount;
    mt = mc*2 + (member >> 2);
    nt = member & 3;
  } else { mt = blockIdx.x; nt = blockIdx.y; zt = blockIdx.z; }
  int tid = threadIdx.x;
  int wave = tid >> 6, lane = tid & 63;
  int m0 = mt * 128, n0 = nt * 128;
  int kStart = zt * kPerZ;
  int waveM = wave >> 1, waveN = wave & 1;
  int lr = lane >> 2, ch = lane & 3;
  int quad = lane >> 4, mrow = lane & 15;
  int swe = ((quad ^ (mrow & 3)) << 3);

  int rA0 = wave*32 + lr;
  int rA1 = rA0 + 16;
  int ce  = ((ch ^ (rA0 & 3)) << 3);
  const unsigned short* gA0 = A  + (long)(m0 + rA0)*lda + kStart + ce;
  const unsigned short* gA1 = A  + (long)(m0 + rA1)*lda + kStart + ce;
  const unsigned short* gB0 = BT + (long)(n0 + rA0)*ldb + kStart + ce;
  const unsigned short* gB1 = BT + (long)(n0 + rA1)*ldb + kStart + ce;
  unsigned short* lA0 = &As[(wave*32)*32];
  unsigned short* lA1 = &As[(wave*32+16)*32];
  unsigned short* lB0 = &Bs[(wave*32)*32];
  unsigned short* lB1 = &Bs[(wave*32+16)*32];

  f32x4 acc[4][4] = {};
  int nIter = kPerZ >> 5;
  for (int it = 0; it < nIter; ++it){
    long ko = (long)it << 5;
    load_lds16(gA0 + ko, lA0);
    load_lds16(gA1 + ko, lA1);
    load_lds16(gB0 + ko, lB0);
    load_lds16(gB1 + ko, lB1);
    __syncthreads();
    bf16x8 af[4], bfr[4];
#pragma unroll
    for (int mi = 0; mi < 4; mi++)
      af[mi] = *(const bf16x8*)&As[(waveM*64 + mi*16 + mrow)*32 + swe];
#pragma unroll
    for (int ni = 0; ni < 4; ni++)
      bfr[ni] = *(const bf16x8*)&Bs[(waveN*64 + ni*16 + mrow)*32 + swe];
#pragma unroll
    for (int mi = 0; mi < 4; mi++)
#pragma unroll
      for (int ni = 0; ni < 4; ni++)
        acc[mi][ni] = __builtin_amdgcn_mfma_f32_16x16x32_bf16(
            af[mi], bfr[ni], acc[mi][ni], 0, 0, 0);
    __syncthreads();
  }
  if (RELU){
    unsigned short* C = (unsigned short*)Cv;
#pragma unroll
    for (int mi = 0; mi < 4; mi++)
#pragma unroll
      for (int ni = 0; ni < 4; ni++){
        int col = n0 + waveN*64 + ni*16 + mrow;
#pragma unroll
        for (int r = 0; r < 4; r++){
          int row = m0 + waveM*64 + mi*16 + quad*4 + r;
          C[(long)row*ldc + col] = f2bf(fmaxf(acc[mi][ni][r], 0.f));
        }
      }
  } else {
    float* C = (float*)Cv + (long)zt * cStrideZ;
#pragma unroll
    for (int mi = 0; mi < 4; mi++)
#pragma unroll
      for (int ni = 0; ni < 4; ni++){
        int col = n0 + waveN*64 + ni*16 + mrow;
#pragma unroll
        for (int r = 0; r < 4; r++){
          int row = m0 + waveM*64 + mi*16 + quad*4 + r;
          C[(long)row*ldc + col] = acc[mi][ni][r];
        }
      }
  }
}
template __global__ void k_mfma<true>(const unsigned short*, long, const unsigned short*, long, void*, int, int, long, int);
template __global__ void k_mfma<false>(const unsigned short*, long, const unsigned short*, long, void*, int, int, long, int);

// ---------------------------------------------------------------------------
// k_dual: cheby2 (blocks [0,320)) + cheby1 (blocks [320,2304)) in one
// dispatch.  Both are bf16 GEMM + relu store, 128x128 tile, zt=0.
//   cheby2: (10240 x 768) @ (768 x 512)^T  mc=40
//   cheby1: (63488 x 384) @ (384 x 512)^T  mc=248
// ---------------------------------------------------------------------------
__global__ __launch_bounds__(256) void k_dual(
    const unsigned short* __restrict__ A2c, const unsigned short* __restrict__ B2c,
    unsigned short* __restrict__ C2c,
    const unsigned short* __restrict__ A1c, const unsigned short* __restrict__ B1c,
    unsigned short* __restrict__ C1c){
  __shared__ unsigned short As[128*32];
  __shared__ unsigned short Bs[128*32];
  int id = blockIdx.x;
  bool is1 = id >= 320;
  const unsigned short* A  = is1 ? A1c : A2c;
  const unsigned short* BT = is1 ? B1c : B2c;
  unsigned short* C = is1 ? C1c : C2c;
  long lda = is1 ? 384 : 768;
  long ldb = lda;
  int kPerZ = (int)lda;
  if (is1) id -= 320;
  int c = ((id >> 6) << 3) + (id & 7);
  int member = (id >> 3) & 7;
  int mt = c*2 + (member >> 2);
  int nt = member & 3;
  int tid = threadIdx.x;
  int wave = tid >> 6, lane = tid & 63;
  int m0 = mt * 128, n0 = nt * 128;
  int waveM = wave >> 1, waveN = wave & 1;
  int lr = lane >> 2, ch = lane & 3;
  int quad = lane >> 4, mrow = lane & 15;
  int swe = ((quad ^ (mrow & 3)) << 3);

  int rA0 = wave*32 + lr;
  int rA1 = rA0 + 16;
  int ce  = ((ch ^ (rA0 & 3)) << 3);
  const unsigned short* gA0 = A  + (long)(m0 + rA0)*lda + ce;
  const unsigned short* gA1 = A  + (long)(m0 + rA1)*lda + ce;
  const unsigned short* gB0 = BT + (long)(n0 + rA0)*ldb + ce;
  const unsigned short* gB1 = BT + (long)(n0 + rA1)*ldb + ce;
  unsigned short* lA0 = &As[(wave*32)*32];
  unsigned short* lA1 = &As[(wave*32+16)*32];
  unsigned short* lB0 = &Bs[(wave*32)*32];
  unsigned short* lB1 = &Bs[(wave*32+16)*32];

  f32x4 acc[4][4] = {};
  int nIter = kPerZ >> 5;
  for (int it = 0; it < nIter; ++it){
    long ko = (long)it << 5;
    load_lds16(gA0 + ko, lA0);
    load_lds16(gA1 + ko, lA1);
    load_lds16(gB0 + ko, lB0);
    load_lds16(gB1 + ko, lB1);
    __syncthreads();
    bf16x8 af[4], bfr[4];
#pragma unroll
    for (int mi = 0; mi < 4; mi++)
      af[mi] = *(const bf16x8*)&As[(waveM*64 + mi*16 + mrow)*32 + swe];
#pragma unroll
    for (int ni = 0; ni < 4; ni++)
      bfr[ni] = *(const bf16x8*)&Bs[(waveN*64 + ni*16 + mrow)*32 + swe];
#pragma unroll
    for (int mi = 0; mi < 4; mi++)
#pragma unroll
      for (int ni = 0; ni < 4; ni++)
        acc[mi][ni] = __builtin_amdgcn_mfma_f32_16x16x32_bf16(
            af[mi], bfr[ni], acc[mi][ni], 0, 0, 0);
    __syncthreads();
  }
#pragma unroll
  for (int mi = 0; mi < 4; mi++)
#pragma unroll
    for (int ni = 0; ni < 4; ni++){
      int col = n0 + waveN*64 + ni*16 + mrow;
#pragma unroll
      for (int r = 0; r < 4; r++){
        int row = m0 + waveM*64 + mi*16 + quad*4 + r;
        C[(long)row*512 + col] = f2bf(fmaxf(acc[mi][ni][r], 0.f));
      }
    }
}

// ---------------------------------------------------------------------------
// k_mid: blocks [0,1024) = spread2 via MFMA (XCAT slots 1,2); blocks
// [1024,1184) = region MFMA GEMM (g2in).  Both depend only on ARb.
// spread2: per b, D(64n x 128c) = Ab/A2b(64x64, bf16, zero-padded) @
// gT(64m x 128c).  LDS: gT[128][64] swizzled (16 KB) + Ab/A2b copies (16 KB).
// 4 waves = {matrix} x {c-half}; 2 k-steps of 32; 32 MFMA/wave.
// ---------------------------------------------------------------------------
__global__ __launch_bounds__(256) void k_mid(
    const unsigned short* __restrict__ ARb, const unsigned short* __restrict__ Ab,
    const unsigned short* __restrict__ A2b, unsigned short* __restrict__ xcat,
    const unsigned short* __restrict__ RWT, const float* __restrict__ regb,
    float* __restrict__ g2in){
  __shared__ __align__(16) char smraw[32768];
  int id = blockIdx.x;
  int tid = threadIdx.x;
  if (id < 1024){
    // ---- spread2 MFMA: XCAT slot1 = bf16(A @ g_b), slot2 = bf16(A^2 @ g_b)
    unsigned short* gT  = (unsigned short*)smraw;   // [128 c][64 m] swizzled
    unsigned short* AbL = gT + 128*64;              // [2][64 n][64 m] swizzled
    int b = id;
    const unsigned short* arp = ARb + (long)b*7936;
    for (int i = tid; i < 7936; i += 256){
      int p = i >> 7, c = i & 127;
      int m = cOrder[p];
      gT[(c<<6) + (((m>>3) ^ (c&7))<<3) + (m&7)] = arp[i];
    }
    { // zero-pad k rows m=62,63 (chunk 7 of every c row)
      int c = tid >> 1, m = 62 + (tid & 1);
      gT[(c<<6) + ((7 ^ (c&7))<<3) + (m&7)] = 0;
    }
    for (int q = tid; q < 1024; q += 256){
      int mm = q >> 9, qq = q & 511;
      int row = qq >> 3, ch = qq & 7;
      const unsigned short* src = mm ? A2b : Ab;
      *(bf16x8*)&AbL[mm*4096 + (row<<6) + ((ch ^ (row&7))<<3)] =
        *(const bf16x8*)&src[(row<<6) + (ch<<3)];
    }
    __syncthreads();
    int wave = tid >> 6, lane = tid & 63;
    int quad = lane >> 4, mrow = lane & 15;
    int mat = wave >> 1, wc = wave & 1;
    const unsigned short* Am = AbL + mat*4096;
    f32x4 acc[4][4] = {};
#pragma unroll
    for (int s = 0; s < 2; s++){
      bf16x8 af[4], bfr[4];
#pragma unroll
      for (int mi = 0; mi < 4; mi++){
        int row = mi*16 + mrow;
        af[mi] = *(const bf16x8*)&Am[(row<<6) + ((((s<<2)|quad) ^ (row&7))<<3)];
      }
#pragma unroll
      for (int ni = 0; ni < 4; ni++){
        int row = wc*64 + ni*16 + mrow;
        bfr[ni] = *(const bf16x8*)&gT[(row<<6) + ((((s<<2)|quad) ^ (row&7))<<3)];
      }
#pragma unroll
      for (int mi = 0; mi < 4; mi++)
#pragma unroll
        for (int ni = 0; ni < 4; ni++)
          acc[mi][ni] = __builtin_amdgcn_mfma_f32_16x16x32_bf16(
              af[mi], bfr[ni], acc[mi][ni], 0, 0, 0);
    }
    long xb = (long)b*23808 + (mat+1)*128;
#pragma unroll
    for (int mi = 0; mi < 4; mi++)
#pragma unroll
      for (int ni = 0; ni < 4; ni++){
        int c = wc*64 + ni*16 + mrow;
#pragma unroll
        for (int r = 0; r < 4; r++){
          int n = mi*16 + quad*4 + r;
          if (n < 62) xcat[xb + (long)n*384 + c] = f2bf(acc[mi][ni][r]);
        }
      }
    return;
  }
  // ---- region GEMM: g2in[b, z*256+m] = ARb[b, cum_z:]*RWT_z^T + regb ----
  unsigned short* As = (unsigned short*)smraw;          // 128*32 shorts
  unsigned short* Bs = As + 128*32;                     // 128*32 shorts
  int id2 = id - 1024;
  int z = id2 >> 4;
  int m  = id2 & 15;
  int mt = m >> 1, nt = m & 1;
  int K = cRegK[z];
  int cumk = cRegCum[z];
  const unsigned short* A  = ARb + cumk;
  const unsigned short* BT = RWT + (long)cumk*256;
  long lda = 7936, ldb = K;
  int wave = tid >> 6, lane = tid & 63;
  int m0 = mt * 128, n0 = nt * 128;
  int waveM = wave >> 1, waveN = wave & 1;
  int lr = lane >> 2, ch = lane & 3;
  int quad = lane >> 4, mrow = lane & 15;
  int swe = ((quad ^ (mrow & 3)) << 3);

  int rA0 = wave*32 + lr;
  int rA1 = rA0 + 16;
  int ce  = ((ch ^ (rA0 & 3)) << 3);
  const unsigned short* gA0 = A  + (long)(m0 + rA0)*lda + ce;
  const unsigned short* gA1 = A  + (long)(m0 + rA1)*lda + ce;
  const unsigned short* gB0 = BT + (long)(n0 + rA0)*ldb + ce;
  const unsigned short* gB1 = BT + (long)(n0 + rA1)*ldb + ce;
  unsigned short* lA0 = &As[(wave*32)*32];
  unsigned short* lA1 = &As[(wave*32+16)*32];
  unsigned short* lB0 = &Bs[(wave*32)*32];
  unsigned short* lB1 = &Bs[(wave*32+16)*32];

  f32x4 acc[4][4] = {};
  int nIter = K >> 5;
  for (int it = 0; it < nIter; ++it){
    long ko = (long)it << 5;
    load_lds16(gA0 + ko, lA0);
    load_lds16(gA1 + ko, lA1);
    load_lds16(gB0 + ko, lB0);
    load_lds16(gB1 + ko, lB1);
    __syncthreads();
    bf16x8 af[4], bfr[4];
#pragma unroll
    for (int mi = 0; mi < 4; mi++)
      af[mi] = *(const bf16x8*)&As[(waveM*64 + mi*16 + mrow)*32 + swe];
#pragma unroll
    for (int ni = 0; ni < 4; ni++)
      bfr[ni] = *(const bf16x8*)&Bs[(waveN*64 + ni*16 + mrow)*32 + swe];
#pragma unroll
    for (int mi = 0; mi < 4; mi++)
#pragma unroll
      for (int ni = 0; ni < 4; ni++)
        acc[mi][ni] = __builtin_amdgcn_mfma_f32_16x16x32_bf16(
            af[mi], bfr[ni], acc[mi][ni], 0, 0, 0);
    __syncthreads();
  }
#pragma unroll
  for (int mi = 0; mi < 4; mi++)
#pragma unroll
    for (int ni = 0; ni < 4; ni++){
      int col = n0 + waveN*64 + ni*16 + mrow;
      float bias = regb[z*256 + col];
#pragma unroll
      for (int r = 0; r < 4; r++){
        int row = m0 + waveM*64 + mi*16 + quad*4 + r;
        g2in[(long)row*2560 + z*256 + col] = acc[mi][ni][r] + bias;
      }
    }
}

// ---------------------------------------------------------------------------
// k_front: one dispatch for all input-only work.
//   [0,4784)        : 64x64 fp32->bf16 transpose tiles (hc_w1/hc_w2/ch1w/ch2w)
//   [4784,7344)     : region-weight transpose
//   [7344,7406)     : bf16 A (row-major, 64x64 zero-padded) + bf16 (A@A)
//   [7406,15342)    : g-kernel, 8 (b,n) rows/block, float4 channel loads
//   [15342,15344)   : zero bn stat accumulators + spin counters (2048 floats)
// ---------------------------------------------------------------------------
__global__ __launch_bounds__(256) void k_front(
    const float* __restrict__ s0, unsigned short* __restrict__ d0,
    const float* __restrict__ s1, unsigned short* __restrict__ d1,
    const float* __restrict__ s2, unsigned short* __restrict__ d2,
    const float* __restrict__ s3, unsigned short* __restrict__ d3,
    Ptr10 rws, unsigned short* __restrict__ RWT,
    const float* __restrict__ Amat, unsigned short* __restrict__ AbW,
    unsigned short* __restrict__ A2bW,
    const float* __restrict__ x, const float* __restrict__ tw,
    const float* __restrict__ tb, unsigned short* __restrict__ arb,
    unsigned short* __restrict__ xcat, float* __restrict__ sumz){
  __shared__ float smem[64*65];
  int id = blockIdx.x;
  int tid = threadIdx.x;
  if (id >= 15342){
    *(float4*)(sumz + (id-15342)*1024 + tid*4) = make_float4(0.f,0.f,0.f,0.f);
    return;
  }
  if (id >= 7406){
    // g[b,n,c] = (sum_i x*tfe_w + tfe_b) * exp(-var_i(x)) (ddof=1), bf16 out
    int q = id - 7406;
    int r = tid >> 5, j = tid & 31;        // 8 rows x 32 lanes, 4 ch/lane
    int idx = q*8 + r;                      // b*62+n
    int b = idx / 62, n = idx - b*62;
    const float4* xp = (const float4*)(x + (long)idx*1280) + j;
    float sx=0.f,sy=0.f,sz=0.f,sw=0.f;
    float qx=0.f,qy=0.f,qz=0.f,qw=0.f;
    float gx=0.f,gy=0.f,gz=0.f,gw=0.f;
#pragma unroll
    for (int i = 0; i < 10; i++){
      float4 v = xp[i*32];
      float w = tw[n*10+i];
      sx+=v.x; sy+=v.y; sz+=v.z; sw+=v.w;
      qx=fmaf(v.x,v.x,qx); qy=fmaf(v.y,v.y,qy);
      qz=fmaf(v.z,v.z,qz); qw=fmaf(v.w,v.w,qw);
      gx=fmaf(v.x,w,gx); gy=fmaf(v.y,w,gy);
      gz=fmaf(v.z,w,gz); gw=fmaf(v.w,w,gw);
    }
    float tbn = tb[n];
    float mx_=sx*0.1f, my_=sy*0.1f, mz_=sz*0.1f, mw_=sw*0.1f;
    float rx = (gx+tbn)*expf(-(qx-10.f*mx_*mx_)*(1.f/9.f));
    float ry = (gy+tbn)*expf(-(qy-10.f*my_*my_)*(1.f/9.f));
    float rz = (gz+tbn)*expf(-(qz-10.f*mz_*mz_)*(1.f/9.f));
    float rw = (gw+tbn)*expf(-(qw-10.f*mw_*mw_)*(1.f/9.f));
    ushort4 u = make_ushort4(f2bf(rx), f2bf(ry), f2bf(rz), f2bf(rw));
    *(ushort4*)(arb  + (long)b*7936  + cPos[n]*128 + j*4) = u;
    *(ushort4*)(xcat + (long)b*23808 + n*384       + j*4) = u;
    return;
  }
  if (id < 7344 && id >= 4784){
    // region-weight transpose: RWT[cum+m*K + l*128+c] = bf16(rw[m][c*L+l])
    int q = id - 4784;
    int z = q >> 8, m = q & 255;
    int K = cRegK[z], L = K >> 7;
    const float* rw = rws.p[z] + (long)m*K;
    unsigned short* dst = RWT + (long)cRegCum[z]*256 + (long)m*K;
    for (int i = tid; i < K; i += 256) smem[i] = rw[i];
    __syncthreads();
    for (int k = tid; k < K; k += 256){
      int l = k >> 7, c = k & 127;
      dst[k] = f2bf(smem[c*L + l]);
    }
    return;
  }
  if (id >= 7344){
    // A helpers, one row per block: Ab[r][c]=bf16(A[r][c]), A2b=bf16((A@A)[r][c])
    int r = id - 7344, c = tid;
    if (c < 62) smem[c] = Amat[r*62 + c];
    __syncthreads();
    if (c < 64){
      unsigned short av = 0, a2v = 0;
      if (c < 62){
        av = f2bf(smem[c]);
        float s = 0.f;
        for (int t = 0; t < 62; t++) s = fmaf(smem[t], Amat[t*62 + c], s);
        a2v = f2bf(s);
      }
      AbW [r*64 + c] = av;
      A2bW[r*64 + c] = a2v;
    }
    // zero-pad rows 62,63 once (block r==0, threads 64..191)
    if (r == 0 && c >= 64 && c < 192){
      int q = c - 64;                 // 0..127
      int rr = 62 + (q >> 6), cc = q & 63;
      AbW [rr*64 + cc] = 0;
      A2bW[rr*64 + cc] = 0;
    }
    return;
  }
  // 64x64 fp32->bf16 transpose tiles
  const float* src; unsigned short* dst; int R, C, rt, ct;
  if (id < 4608){ src=s0; dst=d0; R=36864; C=512; rt=id>>3;  ct=id&7; }
  else if (id < 4640){ int q=id-4608; src=s1; dst=d1; R=512; C=256; rt=q>>2; ct=q&3; }
  else if (id < 4688){ int q=id-4640; src=s2; dst=d2; R=384; C=512; rt=q>>3; ct=q&7; }
  else { int q=id-4688; src=s3; dst=d3; R=768; C=512; rt=q>>3; ct=q&7; }
  int r0 = rt*64, c0 = ct*64;
  int rr = tid >> 2, cb = (tid & 3) << 2;
#pragma unroll
  for (int i = 0; i < 4; i++){
    int cc = cb + i*16;
    float4 v = *(const float4*)(src + (long)(r0+rr)*C + c0 + cc);
    smem[rr*65+cc+0]=v.x; smem[rr*65+cc+1]=v.y;
    smem[rr*65+cc+2]=v.z; smem[rr*65+cc+3]=v.w;
  }
  __syncthreads();
  int cc = tid >> 2, rb = (tid & 3) << 2;
#pragma unroll
  for (int i = 0; i < 4; i++){
    int r = rb + i*16;
    ushort4 u = make_ushort4(f2bf(smem[(r+0)*65+cc]), f2bf(smem[(r+1)*65+cc]),
                             f2bf(smem[(r+2)*65+cc]), f2bf(smem[(r+3)*65+cc]));
    *(ushort4*)(dst + (long)(c0+cc)*R + r0 + r) = u;
  }
}

// ---------------------------------------------------------------------------
// 4) X2cat[b, n, k*256+t] = (A1^k @ g2in[b])[n,t], k=0..2  (bf16 out)
// ---------------------------------------------------------------------------
__global__ __launch_bounds__(256) void k_x2cat(
    const float* __restrict__ g2in, const float* __restrict__ A1,
    unsigned short* __restrict__ X2){
  __shared__ float sg[2560];
  __shared__ float sA1[100];
  __shared__ float sA2[100];
  int b = blockIdx.x, tid = threadIdx.x;
  for (int i = tid; i < 2560; i += 256) sg[i] = g2in[(long)b*2560 + i];
  if (tid < 100) sA1[tid] = A1[tid];
  __syncthreads();
  if (tid < 100){
    int n = tid/10, m = tid - n*10;
    float a = 0.f;
#pragma unroll
    for (int t = 0; t < 10; t++) a = fmaf(sA1[n*10+t], sA1[t*10+m], a);
    sA2[tid] = a;
  }
  __syncthreads();
  for (int i = tid; i < 2560; i += 256){
    int n = i >> 8, t = i & 255;
    float v1 = 0.f, v2 = 0.f;
#pragma unroll
    for (int m = 0; m < 10; m++){
      float gv = sg[(m<<8) + t];
      v1 = fmaf(sA1[n*10+m], gv, v1);
      v2 = fmaf(sA2[n*10+m], gv, v2);
    }
    long base = (long)b*7680 + n*768;
    X2[base + t]       = f2bf(sg[i]);
    X2[base + 256 + t] = f2bf(v1);
    X2[base + 512 + t] = f2bf(v2);
  }
}

// ---------------------------------------------------------------------------
// 6) softmax-gated concat, all per-thread state in registers (no LDS).
//    grid (1024, 2) x 256 thr; thread owns one (b, o) column.
// ---------------------------------------------------------------------------
__global__ __launch_bounds__(256) void k_softcat(
    const unsigned short* __restrict__ g1, const unsigned short* __restrict__ g2,
    const float* __restrict__ bg_, const float* __restrict__ cg_,
    unsigned short* __restrict__ outb){
  int b = blockIdx.x;
  int o = blockIdx.y*256 + threadIdx.x;
  float v[72];
  const unsigned short* p1 = g1 + (long)b*62*512 + o;
#pragma unroll
  for (int j = 0; j < 62; j++) v[j] = bf2f(p1[j*512]);
  const unsigned short* p2 = g2 + (long)b*10*512 + o;
#pragma unroll
  for (int j = 0; j < 10; j++) v[62+j] = bf2f(p2[j*512]);
  float bg = *bg_, cg = *cg_;
  float mx = -1e30f;
#pragma unroll
  for (int j = 0; j < 72; j++){
    float av = (j < 62 ? bg : cg) * v[j];
    mx = fmaxf(mx, av);
  }
  float sum = 0.f;
#pragma unroll
  for (int j = 0; j < 72; j++){
    float e = expf((j < 62 ? bg : cg) * v[j] - mx);
    sum += e;
    v[j] = e * v[j];
  }
  float inv = 1.f / sum;
  unsigned short* op = outb + (long)b*36864 + o;
#pragma unroll
  for (int j = 0; j < 72; j++) op[j*512] = f2bf(v[j] * inv);
}

// ---------------------------------------------------------------------------
// k_tail1: 128 co-resident blocks.  Phase A: reduce 16 split-K partials
// (block = 8 rows x 512 cols, values kept in registers), accumulate column
// sum/sumsq via fp32 atomics.  Spin on release/acquire counter until all
// 128 blocks done.  Phase B: finalize mu/rs, bn1+gelu, write H1B bf16.
// H1 never materialized.
// ---------------------------------------------------------------------------
__global__ __launch_bounds__(256) void k_tail1(
    const float4* __restrict__ P, const float* __restrict__ gam,
    const float* __restrict__ bet, float* __restrict__ sum,
    float* __restrict__ ssq, unsigned int* __restrict__ cnt,
    unsigned short* __restrict__ h1b){
  __shared__ float4 ls[128], ls2[128];
  int tid = threadIdx.x;
  int c  = tid & 127;        // float4-column
  int rr = tid >> 7;         // 0/1
  int r0 = blockIdx.x * 8;
  float4 va[4];
  float4 s1 = make_float4(0.f,0.f,0.f,0.f);
  float4 s2 = make_float4(0.f,0.f,0.f,0.f);
#pragma unroll
  for (int k = 0; k < 4; k++){
    int row = r0 + rr + 2*k;
    long idx = (long)row*128 + c;
    float4 v = make_float4(0.f,0.f,0.f,0.f);
#pragma unroll
    for (int s = 0; s < 16; s++){
      float4 p = P[(long)s*131072 + idx];
      v.x += p.x; v.y += p.y; v.z += p.z; v.w += p.w;
    }
    va[k] = v;
    s1.x += v.x; s1.y += v.y; s1.z += v.z; s1.w += v.w;
    s2.x = fmaf(v.x,v.x,s2.x); s2.y = fmaf(v.y,v.y,s2.y);
    s2.z = fmaf(v.z,v.z,s2.z); s2.w = fmaf(v.w,v.w,s2.w);
  }
  if (rr){ ls[c] = s1; ls2[c] = s2; }
  __syncthreads();
  if (!rr){
    float4 o1 = ls[c], o2 = ls2[c];
    atomicAdd(&sum[c*4+0], s1.x+o1.x); atomicAdd(&sum[c*4+1], s1.y+o1.y);
    atomicAdd(&sum[c*4+2], s1.z+o1.z); atomicAdd(&sum[c*4+3], s1.w+o1.w);
    atomicAdd(&ssq[c*4+0], s2.x+o2.x); atomicAdd(&ssq[c*4+1], s2.y+o2.y);
    atomicAdd(&ssq[c*4+2], s2.z+o2.z); atomicAdd(&ssq[c*4+3], s2.w+o2.w);
  }
  __threadfence();
  __syncthreads();
  if (tid == 0){
    __hip_atomic_fetch_add(cnt, 1u, __ATOMIC_RELEASE, __HIP_MEMORY_SCOPE_AGENT);
    while (__hip_atomic_load(cnt, __ATOMIC_ACQUIRE, __HIP_MEMORY_SCOPE_AGENT) < 128u)
      __builtin_amdgcn_s_sleep(16);
  }
  __syncthreads();
  int j = c*4;
  float mu0 = __hip_atomic_load(&sum[j+0], __ATOMIC_RELAXED, __HIP_MEMORY_SCOPE_AGENT)*(1.f/1024.f);
  float mu1 = __hip_atomic_load(&sum[j+1], __ATOMIC_RELAXED, __HIP_MEMORY_SCOPE_AGENT)*(1.f/1024.f);
  float mu2 = __hip_atomic_load(&sum[j+2], __ATOMIC_RELAXED, __HIP_MEMORY_SCOPE_AGENT)*(1.f/1024.f);
  float mu3 = __hip_atomic_load(&sum[j+3], __ATOMIC_RELAXED, __HIP_MEMORY_SCOPE_AGENT)*(1.f/1024.f);
  float q0 = __hip_atomic_load(&ssq[j+0], __ATOMIC_RELAXED, __HIP_MEMORY_SCOPE_AGENT);
  float q1 = __hip_atomic_load(&ssq[j+1], __ATOMIC_RELAXED, __HIP_MEMORY_SCOPE_AGENT);
  float q2 = __hip_atomic_load(&ssq[j+2], __ATOMIC_RELAXED, __HIP_MEMORY_SCOPE_AGENT);
  float q3 = __hip_atomic_load(&ssq[j+3], __ATOMIC_RELAXED, __HIP_MEMORY_SCOPE_AGENT);
  float rs0 = rsqrtf(q0*(1.f/1024.f) - mu0*mu0 + 1e-5f);
  float rs1 = rsqrtf(q1*(1.f/1024.f) - mu1*mu1 + 1e-5f);
  float rs2 = rsqrtf(q2*(1.f/1024.f) - mu2*mu2 + 1e-5f);
  float rs3 = rsqrtf(q3*(1.f/1024.f) - mu3*mu3 + 1e-5f);
  float g0 = gam[j+0], g1 = gam[j+1], g2 = gam[j+2], g3 = gam[j+3];
  float b0 = bet[j+0], b1 = bet[j+1], b2 = bet[j+2], b3 = bet[j+3];
#pragma unroll
  for (int k = 0; k < 4; k++){
    int row = r0 + rr + 2*k;
    float4 v = va[k];
    ushort4 u;
    u.x = f2bf(gelu_exact((v.x - mu0)*rs0*g0 + b0));
    u.y = f2bf(gelu_exact((v.y - mu1)*rs1*g1 + b1));
    u.z = f2bf(gelu_exact((v.z - mu2)*rs2*g2 + b2));
    u.w = f2bf(gelu_exact((v.w - mu3)*rs3*g3 + b3));
    *(ushort4*)(h1b + (long)row*512 + j) = u;
  }
}

// ---------------------------------------------------------------------------
// k_tail2: 32 co-resident blocks.  Block owns 32 rows x 256 cols.
// Phase A: reduce 4 split-K h2 partials into registers, atomic col stats.
// Spin.  Phase B: bn2+gelu, dot with hc_w3 (+b3), softmax over 4, write out.
// H2 never materialized.
// ---------------------------------------------------------------------------
__global__ __launch_bounds__(256) void k_tail2(
    const float* __restrict__ P2, const float* __restrict__ gam,
    const float* __restrict__ bet, const float* __restrict__ w3,
    const float* __restrict__ b3, float* __restrict__ sum,
    float* __restrict__ ssq, unsigned int* __restrict__ cnt,
    float* __restrict__ outp){
  __shared__ float lv[32][257];
  __shared__ float rd[32][8][4];
  int tid = threadIdx.x;          // col 0..255
  int rbase = blockIdx.x * 32;
  float v[32];
  float s = 0.f, s2 = 0.f;
#pragma unroll 8
  for (int r = 0; r < 32; r++){
    int row = rbase + r;
    float a = 0.f;
#pragma unroll
    for (int sp = 0; sp < 4; sp++)
      a += P2[((long)sp*1024 + row)*256 + tid];
    v[r] = a;
    s += a; s2 = fmaf(a, a, s2);
  }
  atomicAdd(&sum[tid], s);
  atomicAdd(&ssq[tid], s2);
  __threadfence();
  __syncthreads();
  if (tid == 0){
    __hip_atomic_fetch_add(cnt, 1u, __ATOMIC_RELEASE, __HIP_MEMORY_SCOPE_AGENT);
    while (__hip_atomic_load(cnt, __ATOMIC_ACQUIRE, __HIP_MEMORY_SCOPE_AGENT) < 32u)
      __builtin_amdgcn_s_sleep(16);
  }
  __syncthreads();
  float mu = __hip_atomic_load(&sum[tid], __ATOMIC_RELAXED, __HIP_MEMORY_SCOPE_AGENT)*(1.f/1024.f);
  float qq = __hip_atomic_load(&ssq[tid], __ATOMIC_RELAXED, __HIP_MEMORY_SCOPE_AGENT);
  float rs = rsqrtf(qq*(1.f/1024.f) - mu*mu + 1e-5f);
  float gm = gam[tid], bt = bet[tid];
#pragma unroll 8
  for (int r = 0; r < 32; r++)
    lv[r][tid] = gelu_exact((v[r] - mu)*rs*gm + bt);
  __syncthreads();
  // per-row dot with w3: thread = (row = tid>>3, seg = tid&7)
  int row = tid >> 3, seg = tid & 7;
  float p0=0.f,p1=0.f,p2=0.f,p3=0.f;
#pragma unroll
  for (int i = 0; i < 32; i++){
    int cc = seg*32 + i;
    float a = lv[row][cc];
    float4 w = ((const float4*)w3)[cc];
    p0 = fmaf(a, w.x, p0); p1 = fmaf(a, w.y, p1);
    p2 = fmaf(a, w.z, p2); p3 = fmaf(a, w.w, p3);
  }
  rd[row][seg][0]=p0; rd[row][seg][1]=p1; rd[row][seg][2]=p2; rd[row][seg][3]=p3;
  __syncthreads();
  if (tid < 32){
    float l[4];
#pragma unroll
    for (int c = 0; c < 4; c++){
      float a = 0.f;
#pragma unroll
      for (int g = 0; g < 8; g++) a += rd[tid][g][c];
      l[c] = a + b3[c];
    }
    float m = fmaxf(fmaxf(l[0], l[1]), fmaxf(l[2], l[3]));
    float e[4]; float su = 0.f;
#pragma unroll
    for (int c = 0; c < 4; c++){ e[c] = expf(l[c]-m); su += e[c]; }
    float inv = 1.f / su;
#pragma unroll
    for (int c = 0; c < 4; c++) outp[(long)(rbase+tid)*4 + c] = e[c]*inv;
  }
}

// ---------------------------------------------------------------------------
// Workspace layout (byte offsets), peak ~248 MB.
// Stats block @246415360 (8 KB, zeroed by k_front):
//   SUM1[512] SSQ1[512] SUM2[256] SSQ2[256] CNT1 CNT2 pad
// Ab @246423552 (8 KB bf16 64x64), A2b @246439040 (8 KB).
// ---------------------------------------------------------------------------
extern "C" void kernel_launch(void* const* d_in, const int* in_sizes, int n_in,
                              void* d_out, int out_size, void* d_ws, size_t ws_size,
                              hipStream_t stream){
  (void)n_in; (void)out_size; (void)ws_size;
  bool dictOrder = (in_sizes[9] == 2560);
  const float* x     = (const float*)d_in[0];
  const float* tfe_w = (const float*)d_in[1];
  const float* tfe_b = (const float*)d_in[2];
  const float* ch1w  = (const float*)d_in[3];
  const float* Amat  = (const float*)d_in[4];
  const float* ch2w  = (const float*)d_in[5];
  const float* A1mat = (const float*)d_in[6];
  const float* bgate = (const float*)d_in[7];
  const float* cgate = (const float*)d_in[8];
  const float* regb  = (const float*)d_in[dictOrder ? 9 : 19];
  int o = dictOrder ? 0 : 10;
  const float* hc_w1 = (const float*)d_in[10+o];
  const float* bn1g  = (const float*)d_in[12+o];
  const float* bn1b  = (const float*)d_in[13+o];
  const float* hc_w2 = (const float*)d_in[14+o];
  const float* bn2g  = (const float*)d_in[16+o];
  const float* bn2b  = (const float*)d_in[17+o];
  const float* hc_w3 = (const float*)d_in[18+o];
  const float* hc_b3 = (const float*)d_in[19+o];
  Ptr10 rws;
  for (int i = 0; i < 10; i++) rws.p[i] = (const float*)d_in[(dictOrder ? 20 : 9) + i];

  char* Wb = (char*)d_ws;
  unsigned short* ARb   = (unsigned short*)(Wb + 0);
  unsigned short* XCAT  = (unsigned short*)(Wb + 16252928);
  unsigned short* RWT   = (unsigned short*)(Wb + 65011712);
  float*          G2IN  = (float*)(Wb + 69074944);
  unsigned short* X2CAT = (unsigned short*)(Wb + 79560704);
  unsigned short* W1T   = (unsigned short*)(Wb + 95289344);
  unsigned short* WC1T  = (unsigned short*)(Wb + 133038080);
  unsigned short* WC2T  = (unsigned short*)(Wb + 133431296);
  unsigned short* G1    = (unsigned short*)(Wb + 134217728);
  unsigned short* G2    = (unsigned short*)(Wb + 199229440);
  unsigned short* OUTB  = (unsigned short*)(Wb + 0);
  float*          P     = (float*)(Wb + 209715200);
  float*          SUM1  = (float*)(Wb + 246415360);   // stats block (8 KB)
  float*          SSQ1  = SUM1 + 512;
  float*          SUM2  = SUM1 + 1024;
  float*          SSQ2  = SUM1 + 1280;
  unsigned int*   CNT1  = (unsigned int*)(SUM1 + 1536);
  unsigned int*   CNT2  = (unsigned int*)(SUM1 + 1537);
  unsigned short* Ab    = (unsigned short*)(Wb + 246423552);
  unsigned short* A2b   = (unsigned short*)(Wb + 246439040);
  unsigned short* W2T   = (unsigned short*)(Wb + 246454528);
  unsigned short* H1B   = (unsigned short*)(Wb + 246716928);

  // 1) prep transforms + g + stats-block zeroing
  k_front<<<15344, 256, 0, stream>>>(hc_w1, W1T, hc_w2, W2T, ch1w, WC1T,
                                     ch2w, WC2T, rws, RWT, Amat, Ab, A2b,
                                     x, tfe_w, tfe_b, ARb, XCAT, SUM1);
  // 2) spread2 MFMA (1024 blocks) + region GEMM (160 blocks), one dispatch
  k_mid<<<1184, 256, 0, stream>>>(ARb, Ab, A2b, XCAT, RWT, regb, G2IN);
  // 3) A1-hop concat
  k_x2cat<<<1024, 256, 0, stream>>>(G2IN, A1mat, X2CAT);
  // 4) cheby2 (320 blocks) + cheby1 (1984 blocks), one dispatch
  k_dual<<<2304, 256, 0, stream>>>(X2CAT, WC2T, G2, XCAT, WC1T, G1);
  // 5) softmax-gated concat
  k_softcat<<<dim3(1024,2), 256, 0, stream>>>(G1, G2, bgate, cgate, OUTB);
  // 6) h1: (1024 x 36864) @ (36864 x 512), split-K=16, swizzled 512 blocks
  k_mfma<false><<<512, 256, 0, stream>>>(OUTB, 36864, W1T, 36864, (void*)P, 512, 2304, 524288, 4);
  // 7) fused reduce + bn1 stats + gelu -> H1B
  k_tail1<<<128, 256, 0, stream>>>((const float4*)P, bn1g, bn1b, SUM1, SSQ1, CNT1, H1B);
  // 8) h2: (1024 x 512) @ (512 x 256), split-K=4 (P reused as partials)
  k_mfma<false><<<dim3(8,2,4), 256, 0, stream>>>(H1B, 512, W2T, 512, (void*)P, 256, 128, 262144, 0);
  // 9) fused reduce + bn2 + gelu + w3 dot + softmax -> out
  k_tail2<<<32, 256, 0, stream>>>(P, bn2g, bn2b, hc_w3, hc_b3, SUM2, SSQ2, CNT2, (float*)d_out);
}